// Round 1
// 354.496 us; speedup vs baseline: 1.3268x; 1.3268x over previous
//
#include <hip/hip_runtime.h>
#include <hip/hip_bf16.h>

#define NNODES 50000
#define NEDGES 1600000
#define DD 128
#define EPSF 1e-6f
#define NB_SCAN 196   // ceil(50000/256)

using u32 = unsigned int;
using u16 = unsigned short;

static __device__ __forceinline__ float b2f_lo(u32 w) { return __uint_as_float(w << 16); }
static __device__ __forceinline__ float b2f_hi(u32 w) { return __uint_as_float(w & 0xffff0000u); }
static __device__ __forceinline__ u16 f2b(float f) {
    u32 u = __float_as_uint(f);
    return (u16)((u + 0x7fffu + ((u >> 16) & 1u)) >> 16);
}
static __device__ __forceinline__ float tanh_pos(float a) {   // a >= 0, fast
    float e = __expf(-2.f * a);
    return __fdividef(1.f - e, 1.f + e);
}

// workspace byte offsets
#define OFF_WCOMBT 0          // 128*128 f32 (Wphi@Wchi, transposed)
#define OFF_WCHIT  65536      // 128*128 f32
#define OFF_WVPHIT 131072     // 128*128 f32
#define OFF_PHICHI 196608     // 50000 f32  tanh(||x@Wchi^T||)
#define OFF_CNT    396608     // 50000 u32
#define OFF_START  596608     // 50000 u32
#define OFF_CURSOR 796608     // 50000 u32 (fallback path only)
#define OFF_BSUM   996608     // 196 u32 (padded 1KB)
#define OFF_BOFF   997632     // 196 u32 (padded 1KB)
#define OFF_BLOB   998656     // 50000*384 u16 : per node [z 128][v 128][x 128] bf16
#define OFF_EREC   39398656   // 1.6M uint2 (col, ew) packed records -> ends 52,198,656
#define OFF_RANK   52198656   // 1.6M u32 per-edge rank-within-row  -> ends 58,598,656
#define WS_NEED_RANK 58598656ull

#define HB (NEDGES/256)       // 6250 hist blocks
#define IB (NNODES*DD/4/256)  // 6250 init blocks
#define WB 64                 // weight blocks (64*256 = 128*128)

template<bool RANK>
__global__ __launch_bounds__(256) void k_prep(const int* __restrict__ ei,
                                              const float* __restrict__ x,
                                              const float* __restrict__ Wchi,
                                              const float* __restrict__ Wphi,
                                              const float* __restrict__ Wvphi,
                                              float* __restrict__ ws,
                                              u32* __restrict__ cnt,
                                              u16* __restrict__ blob,
                                              u32* __restrict__ rank) {
    int b = blockIdx.x, t = threadIdx.x;
    if (b < HB) {                                  // histogram (+ per-edge rank)
        int e = b*256 + t;
        if (RANK) rank[e] = atomicAdd(&cnt[ei[e]], 1u);
        else      atomicAdd(&cnt[ei[e]], 1u);
    } else if (b < HB + IB) {                      // x -> bf16 blob
        int idx = (b - HB)*256 + t;
        float4 v = ((const float4*)x)[idx];
        int n  = idx >> 5;
        int d4 = idx & 31;
        u32 p0 = (u32)f2b(v.x) | ((u32)f2b(v.y) << 16);
        u32 p1 = (u32)f2b(v.z) | ((u32)f2b(v.w) << 16);
        *(uint2*)(blob + (size_t)n*384 + 256 + d4*4) = make_uint2(p0, p1);
    } else {                                       // weight transposes + Wcomb
        int w = (b - HB - IB)*256 + t;
        int k = w >> 7, i = w & 127;
        float acc = 0.f;
        #pragma unroll 8
        for (int m = 0; m < DD; ++m)
            acc = fmaf(Wphi[i*DD+m], Wchi[m*DD+k], acc);
        ws[OFF_WCOMBT/4 + k*DD + i] = acc;
        ws[OFF_WCHIT/4  + k*DD + i] = Wchi[i*DD+k];
        ws[OFF_WVPHIT/4 + k*DD + i] = Wvphi[i*DD+k];
    }
}

__global__ __launch_bounds__(256) void k_scan_bsum(const u32* __restrict__ cnt,
                                                   u32* __restrict__ bsum) {
    __shared__ u32 s[256];
    int i = blockIdx.x*256 + threadIdx.x;
    s[threadIdx.x] = (i < NNODES) ? cnt[i] : 0u;
    __syncthreads();
    for (int off = 128; off > 0; off >>= 1) {
        if (threadIdx.x < off) s[threadIdx.x] += s[threadIdx.x + off];
        __syncthreads();
    }
    if (threadIdx.x == 0) bsum[blockIdx.x] = s[0];
}

__global__ __launch_bounds__(256) void k_scan_boff(const u32* __restrict__ bsum,
                                                   u32* __restrict__ boff) {
    __shared__ u32 s[256];
    int t = threadIdx.x;
    u32 v = (t < NB_SCAN) ? bsum[t] : 0u;
    s[t] = v;
    __syncthreads();
    for (int off = 1; off < 256; off <<= 1) {
        u32 a = (t >= off) ? s[t - off] : 0u;
        __syncthreads();
        s[t] += a;
        __syncthreads();
    }
    if (t < NB_SCAN) boff[t] = s[t] - v;           // exclusive
}

__global__ __launch_bounds__(256) void k_scan_final(const u32* __restrict__ cnt,
                                                    const u32* __restrict__ boff,
                                                    u32* __restrict__ start,
                                                    u32* __restrict__ cursor) {
    __shared__ u32 s[256];
    int t = threadIdx.x;
    int i = blockIdx.x*256 + t;
    u32 v = (i < NNODES) ? cnt[i] : 0u;
    s[t] = v;
    __syncthreads();
    for (int off = 1; off < 256; off <<= 1) {
        u32 a = (t >= off) ? s[t - off] : 0u;
        __syncthreads();
        s[t] += a;
        __syncthreads();
    }
    if (i < NNODES) {
        u32 val = boff[blockIdx.x] + (s[t] - v);
        start[i]  = val;
        cursor[i] = val;
    }
}

#define SB (NEDGES/256)       // 6250 scatter blocks
#define NBLK (NNODES/16)      // 3125 node blocks
// grid = SB + NBLK = 9375; roles interleaved: b%3==2 -> GEMM, else scatter

template<bool RANK>
__global__ __launch_bounds__(256) void k_mid(const int* __restrict__ ei,
                                             const float* __restrict__ ew,
                                             const u32* __restrict__ start,
                                             u32* __restrict__ cursor,
                                             const u32* __restrict__ rank,
                                             uint2* __restrict__ erec,
                                             const float* __restrict__ x,
                                             float* __restrict__ ws,
                                             u16* __restrict__ blob) {
    int b = blockIdx.x, t = threadIdx.x;
    int bm3 = b % 3;
    if (bm3 != 2) {                                // scatter into CSR (packed 8B record)
        int e = ((b/3)*2 + bm3)*256 + t;
        int r = ei[e];
        u32 pos;
        if (RANK) pos = start[r] + rank[e];        // no atomic: rank precomputed
        else      pos = atomicAdd(&cursor[r], 1u);
        erec[pos] = make_uint2((u32)ei[NEDGES + e], __float_as_uint(ew[e]));
        return;
    }
    // node role: 16 nodes, waves {chi, comb, varphi}, wave 3 idle after load
    __shared__ float xs[16][DD];
    int nb = (b/3) * 16;
    for (int idx = t; idx < 16*DD/4; idx += 256)
        ((float4*)xs)[idx] = ((const float4*)(x + (size_t)nb*DD))[idx];
    __syncthreads();
    int m = t >> 6, i0 = t & 63;
    if (m == 3) return;
    const float* WT = ws + ((m==0) ? OFF_WCHIT/4 : (m==1) ? OFF_WCOMBT/4 : OFF_WVPHIT/4);
    float acc0[16], acc1[16];
    #pragma unroll
    for (int n=0;n<16;++n){acc0[n]=0.f;acc1[n]=0.f;}
    for (int k4 = 0; k4 < DD/4; ++k4) {
        float2 w0 = ((const float2*)(WT + (4*k4+0)*DD))[i0];
        float2 w1 = ((const float2*)(WT + (4*k4+1)*DD))[i0];
        float2 w2 = ((const float2*)(WT + (4*k4+2)*DD))[i0];
        float2 w3 = ((const float2*)(WT + (4*k4+3)*DD))[i0];
        #pragma unroll
        for (int n=0;n<16;++n) {
            float4 xv = *(const float4*)&xs[n][k4*4];
            acc0[n] = fmaf(xv.x, w0.x, acc0[n]);
            acc0[n] = fmaf(xv.y, w1.x, acc0[n]);
            acc0[n] = fmaf(xv.z, w2.x, acc0[n]);
            acc0[n] = fmaf(xv.w, w3.x, acc0[n]);
            acc1[n] = fmaf(xv.x, w0.y, acc1[n]);
            acc1[n] = fmaf(xv.y, w1.y, acc1[n]);
            acc1[n] = fmaf(xv.z, w2.y, acc1[n]);
            acc1[n] = fmaf(xv.w, w3.y, acc1[n]);
        }
    }
    if (m == 0) {                                  // Phi_chi
        float* phichi = ws + OFF_PHICHI/4;
        float sq[16];
        #pragma unroll
        for (int n=0;n<16;++n) sq[n] = acc0[n]*acc0[n] + acc1[n]*acc1[n];
        #pragma unroll
        for (int mask = 1; mask < 64; mask <<= 1) {
            #pragma unroll
            for (int n=0;n<16;++n) sq[n] += __shfl_xor(sq[n], mask);
        }
        if (i0 < 16)
            phichi[nb + i0] = tanh_pos(sqrtf(sq[i0]));
    } else {
        int off = (m==1) ? 0 : 128;                // z at 0, v at 128
        #pragma unroll
        for (int n=0;n<16;++n) {
            u32 p = (u32)f2b(acc0[n]) | ((u32)f2b(acc1[n]) << 16);
            *(u32*)(blob + (size_t)(nb+n)*384 + off + 2*i0) = p;
        }
    }
}

// one wave per node; 4 edges concurrently (16 lanes each); unroll 2; no output atomics
__global__ __launch_bounds__(256) void k_accum(const float* __restrict__ x,
                                               const float* __restrict__ phichi,
                                               const u32* __restrict__ start,
                                               const u32* __restrict__ cnt,
                                               const uint2* __restrict__ erec,
                                               const u16* __restrict__ blob,
                                               float* __restrict__ out) {
    int lane = threadIdx.x & 63;
    int node = blockIdx.x*4 + (threadIdx.x >> 6);
    int g = lane >> 4, l16 = lane & 15;

    const uint4* bn = (const uint4*)blob + (size_t)node*48;
    uint4 zr = bn[l16];
    uint4 vr = bn[16 + l16];
    float zrf[8], vrf[8];
    {
        u32 zw[4] = {zr.x, zr.y, zr.z, zr.w};
        u32 vw[4] = {vr.x, vr.y, vr.z, vr.w};
        #pragma unroll
        for (int j = 0; j < 4; ++j) {
            zrf[2*j]   = b2f_lo(zw[j]);
            zrf[2*j+1] = b2f_hi(zw[j]);
            vrf[2*j]   = b2f_lo(vw[j]);
            vrf[2*j+1] = b2f_hi(vw[j]);
        }
    }
    u32 s0 = start[node];
    u32 n  = cnt[node];

    float accv[8];
    #pragma unroll
    for (int k = 0; k < 8; ++k) accv[k] = 0.f;
    float sphi = 0.f, wsum = 0.f;

    auto proc = [&](uint4 zc, uint4 vc, uint4 xc, float w) {
        float dot = 0.f, ss = 0.f;
        u32 zw[4] = {zc.x, zc.y, zc.z, zc.w};
        u32 vw[4] = {vc.x, vc.y, vc.z, vc.w};
        #pragma unroll
        for (int j = 0; j < 4; ++j) {
            dot = fmaf(zrf[2*j],   b2f_lo(zw[j]), dot);
            dot = fmaf(zrf[2*j+1], b2f_hi(zw[j]), dot);
            float d0 = vrf[2*j]   - b2f_lo(vw[j]);
            float d1 = vrf[2*j+1] - b2f_hi(vw[j]);
            ss = fmaf(d0, d0, ss);
            ss = fmaf(d1, d1, ss);
        }
        #pragma unroll
        for (int mask = 1; mask < 16; mask <<= 1) {
            dot += __shfl_xor(dot, mask);
            ss  += __shfl_xor(ss,  mask);
        }
        float psi = w * tanh_pos(fabsf(dot)) * tanh_pos(__fdividef(1.f, sqrtf(ss) + EPSF));
        sphi += psi;
        wsum += w;
        u32 xw[4] = {xc.x, xc.y, xc.z, xc.w};
        #pragma unroll
        for (int j = 0; j < 4; ++j) {
            accv[2*j]   = fmaf(psi, b2f_lo(xw[j]), accv[2*j]);
            accv[2*j+1] = fmaf(psi, b2f_hi(xw[j]), accv[2*j+1]);
        }
    };

    u32 p = g;
    for (; p + 4 < n; p += 8) {
        u32 i0 = s0 + p, i1 = s0 + p + 4;
        uint2 r0 = erec[i0], r1 = erec[i1];
        int c0 = (int)r0.x, c1 = (int)r1.x;
        float w0 = __uint_as_float(r0.y), w1 = __uint_as_float(r1.y);
        const uint4* b0 = (const uint4*)blob + (size_t)c0*48;
        const uint4* b1 = (const uint4*)blob + (size_t)c1*48;
        uint4 zc0 = b0[l16], vc0 = b0[16+l16], xc0 = b0[32+l16];
        uint4 zc1 = b1[l16], vc1 = b1[16+l16], xc1 = b1[32+l16];
        proc(zc0, vc0, xc0, w0);
        proc(zc1, vc1, xc1, w1);
    }
    if (p < n) {
        u32 i0 = s0 + p;
        uint2 r0 = erec[i0];
        int c0 = (int)r0.x;
        float w0 = __uint_as_float(r0.y);
        const uint4* b0 = (const uint4*)blob + (size_t)c0*48;
        proc(b0[l16], b0[16+l16], b0[32+l16], w0);
    }

    // reduce across the 4 edge-groups
    #pragma unroll
    for (int mask = 16; mask < 64; mask <<= 1) {
        sphi += __shfl_xor(sphi, mask);
        wsum += __shfl_xor(wsum, mask);
        #pragma unroll
        for (int k = 0; k < 8; ++k) accv[k] += __shfl_xor(accv[k], mask);
    }

    float ia = (n == 0) ? 0.f : __fdividef(1.f, wsum * phichi[node]);

    if (g == 0) {
        float scale = 1.f - ia * sphi;
        const float* xp = x + (size_t)node*DD + l16*8;
        float xv[8];
        *(float4*)&xv[0] = ((const float4*)xp)[0];
        *(float4*)&xv[4] = ((const float4*)xp)[1];
        float4 o0, o1;
        o0.x = xv[0]*scale + ia*accv[0];
        o0.y = xv[1]*scale + ia*accv[1];
        o0.z = xv[2]*scale + ia*accv[2];
        o0.w = xv[3]*scale + ia*accv[3];
        o1.x = xv[4]*scale + ia*accv[4];
        o1.y = xv[5]*scale + ia*accv[5];
        o1.z = xv[6]*scale + ia*accv[6];
        o1.w = xv[7]*scale + ia*accv[7];
        float* po = out + (size_t)node*DD + l16*8;
        ((float4*)po)[0] = o0;
        ((float4*)po)[1] = o1;
    }
}

extern "C" void kernel_launch(void* const* d_in, const int* in_sizes, int n_in,
                              void* d_out, int out_size, void* d_ws, size_t ws_size,
                              hipStream_t stream) {
    const float* x     = (const float*)d_in[0];
    const int*   ei    = (const int*)d_in[1];
    const float* ew    = (const float*)d_in[2];
    const float* Wchi  = (const float*)d_in[3];
    const float* Wphi  = (const float*)d_in[4];
    const float* Wvphi = (const float*)d_in[5];
    float* out = (float*)d_out;
    float* ws  = (float*)d_ws;
    char*  wsb = (char*)d_ws;

    float* phichi = (float*)(wsb + OFF_PHICHI);
    u32*   cnt    = (u32*)  (wsb + OFF_CNT);
    u32*   start  = (u32*)  (wsb + OFF_START);
    u32*   cursor = (u32*)  (wsb + OFF_CURSOR);
    u32*   bsum   = (u32*)  (wsb + OFF_BSUM);
    u32*   boff   = (u32*)  (wsb + OFF_BOFF);
    u16*   blob   = (u16*)  (wsb + OFF_BLOB);
    uint2* erec   = (uint2*)(wsb + OFF_EREC);
    u32*   rank   = (u32*)  (wsb + OFF_RANK);

    bool use_rank = (ws_size >= (size_t)WS_NEED_RANK);

    hipMemsetAsync(wsb + OFF_CNT, 0, 200000, stream);
    if (use_rank) {
        k_prep<true><<<dim3(HB+IB+WB), dim3(256), 0, stream>>>(ei, x, Wchi, Wphi, Wvphi, ws, cnt, blob, rank);
    } else {
        k_prep<false><<<dim3(HB+IB+WB), dim3(256), 0, stream>>>(ei, x, Wchi, Wphi, Wvphi, ws, cnt, blob, rank);
    }
    k_scan_bsum<<<dim3(NB_SCAN), dim3(256), 0, stream>>>(cnt, bsum);
    k_scan_boff<<<dim3(1), dim3(256), 0, stream>>>(bsum, boff);
    k_scan_final<<<dim3(NB_SCAN), dim3(256), 0, stream>>>(cnt, boff, start, cursor);
    if (use_rank) {
        k_mid<true><<<dim3(SB+NBLK), dim3(256), 0, stream>>>(ei, ew, start, cursor, rank, erec, x, ws, blob);
    } else {
        k_mid<false><<<dim3(SB+NBLK), dim3(256), 0, stream>>>(ei, ew, start, cursor, rank, erec, x, ws, blob);
    }
    k_accum<<<dim3(NNODES/4), dim3(256), 0, stream>>>(x, phichi, start, cnt, erec, blob, out);
}

// Round 2
// 299.320 us; speedup vs baseline: 1.5713x; 1.1843x over previous
//
#include <hip/hip_runtime.h>
#include <hip/hip_bf16.h>

#define NNODES 50000
#define NEDGES 1600000
#define DD 128
#define EPSF 1e-6f
#define NB_SCAN 196   // ceil(50000/256)

using u32 = unsigned int;
using u16 = unsigned short;

static __device__ __forceinline__ float b2f_lo(u32 w) { return __uint_as_float(w << 16); }
static __device__ __forceinline__ float b2f_hi(u32 w) { return __uint_as_float(w & 0xffff0000u); }
static __device__ __forceinline__ u16 f2b(float f) {
    u32 u = __float_as_uint(f);
    return (u16)((u + 0x7fffu + ((u >> 16) & 1u)) >> 16);
}
static __device__ __forceinline__ float tanh_pos(float a) {   // a >= 0, fast
    float e = __expf(-2.f * a);
    return __fdividef(1.f - e, 1.f + e);
}

// workspace byte offsets
#define OFF_WCHIT  0          // 128*128 f32  Wchi^T
#define OFF_WA     65536      // 128*128 f32  A = Wcomb^T Wcomb (symmetric), [k*128+i]
#define OFF_WB     131072     // 128*128 f32  B = Wvphi^T Wvphi (symmetric), [k*128+i]
#define OFF_PHICHI 196608     // 50000 f32
#define OFF_VSQ    396608     // 50000 f32   x^T B x per node
#define OFF_CNT    596608     // 50000 u32   (aliased as cursor in fallback path)
#define OFF_START  796608     // 50001 u32 (200016 B)
#define OFF_BSUM   996624     // 196 u32 (800 B)
#define OFF_BOFF   997424     // 196 u32 (800 B)
#define OFF_AB     998224     // 50000*256 u16 : per node [a 128][b 128] bf16 (512B rec)
#define OFF_XB     26598224   // 50000*128 u16 : x bf16 (256B rec)  -> 12.8 MB
#define OFF_EREC   39398224   // 1.6M uint2 (col, ew)               -> ends 52,198,224
#define OFF_WCOMB  39398224   // 128*128 f32 TEMP, overlays EREC (dead before k_mid)
#define OFF_RANK   52198224   // 1.6M u32 rank-within-row           -> ends 58,598,224
#define WS_NEED_RANK 58598224ull

#define HB (NEDGES/256)       // 6250 hist blocks
#define IB (NNODES*DD/4/256)  // 6250 init blocks
#define WB 64                 // weight blocks (Wchi transpose)

template<bool RANK>
__global__ __launch_bounds__(256) void k_prep(const int* __restrict__ ei,
                                              const float* __restrict__ x,
                                              const float* __restrict__ Wchi,
                                              float* __restrict__ ws,
                                              u32* __restrict__ cnt,
                                              u16* __restrict__ xb,
                                              u32* __restrict__ rank) {
    int b = blockIdx.x, t = threadIdx.x;
    if (b < HB) {                                  // histogram (+ per-edge rank)
        int e = b*256 + t;
        if (RANK) rank[e] = atomicAdd(&cnt[ei[e]], 1u);
        else      atomicAdd(&cnt[ei[e]], 1u);
    } else if (b < HB + IB) {                      // x -> bf16 xb
        int idx = (b - HB)*256 + t;
        float4 v = ((const float4*)x)[idx];
        int n  = idx >> 5;
        int d4 = idx & 31;
        u32 p0 = (u32)f2b(v.x) | ((u32)f2b(v.y) << 16);
        u32 p1 = (u32)f2b(v.z) | ((u32)f2b(v.w) << 16);
        *(uint2*)(xb + (size_t)n*128 + d4*4) = make_uint2(p0, p1);
    } else {                                       // Wchi transpose
        int w = (b - HB - IB)*256 + t;
        int k = w >> 7, i = w & 127;
        ws[OFF_WCHIT/4 + k*DD + i] = Wchi[i*DD+k];
    }
}

// 128 blocks: b<64 -> Wcomb = Wphi@Wchi (row-major temp); b>=64 -> B = Wvphi^T Wvphi
__global__ __launch_bounds__(256) void k_w1(const float* __restrict__ Wchi,
                                            const float* __restrict__ Wphi,
                                            const float* __restrict__ Wvphi,
                                            float* __restrict__ wcomb,
                                            float* __restrict__ ws) {
    int b = blockIdx.x, t = threadIdx.x;
    if (b < 64) {
        int idx = b*256 + t;
        int i = idx >> 7, k = idx & 127;
        float acc = 0.f;
        #pragma unroll 8
        for (int m = 0; m < DD; ++m)
            acc = fmaf(Wphi[i*DD+m], Wchi[m*DD+k], acc);
        wcomb[i*DD+k] = acc;
    } else {
        int idx = (b-64)*256 + t;
        int i = idx >> 7, k = idx & 127;
        float acc = 0.f;
        #pragma unroll 8
        for (int m = 0; m < DD; ++m)
            acc = fmaf(Wvphi[m*DD+i], Wvphi[m*DD+k], acc);
        ws[OFF_WB/4 + k*DD + i] = acc;
    }
}

// 64 blocks: A = Wcomb^T Wcomb
__global__ __launch_bounds__(256) void k_w2(const float* __restrict__ wcomb,
                                            float* __restrict__ ws) {
    int idx = blockIdx.x*256 + threadIdx.x;
    int i = idx >> 7, k = idx & 127;
    float acc = 0.f;
    #pragma unroll 8
    for (int m = 0; m < DD; ++m)
        acc = fmaf(wcomb[m*DD+i], wcomb[m*DD+k], acc);
    ws[OFF_WA/4 + k*DD + i] = acc;
}

__global__ __launch_bounds__(256) void k_scan_bsum(const u32* __restrict__ cnt,
                                                   u32* __restrict__ bsum) {
    __shared__ u32 s[256];
    int i = blockIdx.x*256 + threadIdx.x;
    s[threadIdx.x] = (i < NNODES) ? cnt[i] : 0u;
    __syncthreads();
    for (int off = 128; off > 0; off >>= 1) {
        if (threadIdx.x < off) s[threadIdx.x] += s[threadIdx.x + off];
        __syncthreads();
    }
    if (threadIdx.x == 0) bsum[blockIdx.x] = s[0];
}

__global__ __launch_bounds__(256) void k_scan_boff(const u32* __restrict__ bsum,
                                                   u32* __restrict__ boff) {
    __shared__ u32 s[256];
    int t = threadIdx.x;
    u32 v = (t < NB_SCAN) ? bsum[t] : 0u;
    s[t] = v;
    __syncthreads();
    for (int off = 1; off < 256; off <<= 1) {
        u32 a = (t >= off) ? s[t - off] : 0u;
        __syncthreads();
        s[t] += a;
        __syncthreads();
    }
    if (t < NB_SCAN) boff[t] = s[t] - v;           // exclusive
}

__global__ __launch_bounds__(256) void k_scan_final(const u32* __restrict__ cnt,
                                                    const u32* __restrict__ boff,
                                                    u32* __restrict__ start,
                                                    u32* __restrict__ cursor) {
    __shared__ u32 s[256];
    int t = threadIdx.x;
    int i = blockIdx.x*256 + t;
    u32 v = (i < NNODES) ? cnt[i] : 0u;
    s[t] = v;
    __syncthreads();
    for (int off = 1; off < 256; off <<= 1) {
        u32 a = (t >= off) ? s[t - off] : 0u;
        __syncthreads();
        s[t] += a;
        __syncthreads();
    }
    if (i < NNODES) {
        u32 val = boff[blockIdx.x] + (s[t] - v);
        start[i]  = val;
        cursor[i] = val;
        if (i == NNODES-1) start[NNODES] = val + v;
    }
}

#define SB (NEDGES/256)       // 6250 scatter blocks
#define NBLK (NNODES/16)      // 3125 node blocks
// grid = SB + NBLK = 9375; roles interleaved: b%3==2 -> GEMM, else scatter

template<bool RANK>
__global__ __launch_bounds__(256) void k_mid(const int* __restrict__ ei,
                                             const float* __restrict__ ew,
                                             const u32* __restrict__ start,
                                             u32* __restrict__ cursor,
                                             const u32* __restrict__ rank,
                                             uint2* __restrict__ erec,
                                             const float* __restrict__ x,
                                             float* __restrict__ ws,
                                             u16* __restrict__ ab) {
    int b = blockIdx.x, t = threadIdx.x;
    int bm3 = b % 3;
    if (bm3 != 2) {                                // scatter into CSR (packed 8B record)
        int e = ((b/3)*2 + bm3)*256 + t;
        int r = ei[e];
        u32 pos;
        if (RANK) pos = start[r] + rank[e];        // no atomic: rank precomputed
        else      pos = atomicAdd(&cursor[r], 1u);
        erec[pos] = make_uint2((u32)ei[NEDGES + e], __float_as_uint(ew[e]));
        return;
    }
    // node role: 16 nodes, waves {chi, A, B}, wave 3 idle after load
    __shared__ float xs[16][DD];
    int nb = (b/3) * 16;
    for (int idx = t; idx < 16*DD/4; idx += 256)
        ((float4*)xs)[idx] = ((const float4*)(x + (size_t)nb*DD))[idx];
    __syncthreads();
    int m = t >> 6, i0 = t & 63;
    if (m == 3) return;
    const float* WT = ws + ((m==0) ? OFF_WCHIT/4 : (m==1) ? OFF_WA/4 : OFF_WB/4);
    float acc0[16], acc1[16];
    #pragma unroll
    for (int n=0;n<16;++n){acc0[n]=0.f;acc1[n]=0.f;}
    for (int k4 = 0; k4 < DD/4; ++k4) {
        float2 w0 = ((const float2*)(WT + (4*k4+0)*DD))[i0];
        float2 w1 = ((const float2*)(WT + (4*k4+1)*DD))[i0];
        float2 w2 = ((const float2*)(WT + (4*k4+2)*DD))[i0];
        float2 w3 = ((const float2*)(WT + (4*k4+3)*DD))[i0];
        #pragma unroll
        for (int n=0;n<16;++n) {
            float4 xv = *(const float4*)&xs[n][k4*4];
            acc0[n] = fmaf(xv.x, w0.x, acc0[n]);
            acc0[n] = fmaf(xv.y, w1.x, acc0[n]);
            acc0[n] = fmaf(xv.z, w2.x, acc0[n]);
            acc0[n] = fmaf(xv.w, w3.x, acc0[n]);
            acc1[n] = fmaf(xv.x, w0.y, acc1[n]);
            acc1[n] = fmaf(xv.y, w1.y, acc1[n]);
            acc1[n] = fmaf(xv.z, w2.y, acc1[n]);
            acc1[n] = fmaf(xv.w, w3.y, acc1[n]);
        }
    }
    if (m == 0) {                                  // Phi_chi
        float* phichi = ws + OFF_PHICHI/4;
        float sq[16];
        #pragma unroll
        for (int n=0;n<16;++n) sq[n] = acc0[n]*acc0[n] + acc1[n]*acc1[n];
        #pragma unroll
        for (int mask = 1; mask < 64; mask <<= 1) {
            #pragma unroll
            for (int n=0;n<16;++n) sq[n] += __shfl_xor(sq[n], mask);
        }
        if (i0 < 16)
            phichi[nb + i0] = tanh_pos(sqrtf(sq[i0]));
    } else {
        int off = (m==1) ? 0 : 128;                // a at 0, b at 128
        #pragma unroll
        for (int n=0;n<16;++n) {
            u32 p = (u32)f2b(acc0[n]) | ((u32)f2b(acc1[n]) << 16);
            *(u32*)(ab + (size_t)(nb+n)*256 + off + 2*i0) = p;
        }
        if (m == 2) {                              // vsq = x . (B x)
            float* vsq = ws + OFF_VSQ/4;
            float sq[16];
            #pragma unroll
            for (int n=0;n<16;++n)
                sq[n] = acc0[n]*xs[n][2*i0] + acc1[n]*xs[n][2*i0+1];
            #pragma unroll
            for (int mask = 1; mask < 64; mask <<= 1) {
                #pragma unroll
                for (int n=0;n<16;++n) sq[n] += __shfl_xor(sq[n], mask);
            }
            if (i0 < 16)
                vsq[nb + i0] = sq[i0];
        }
    }
}

// one wave per node; 4 edges concurrently (16 lanes each); unroll 2
// per-edge gather: x_c (256B) + vsq_c (4B, L2-resident)
__global__ __launch_bounds__(256) void k_accum(const float* __restrict__ x,
                                               const float* __restrict__ phichi,
                                               const float* __restrict__ vsq,
                                               const u32* __restrict__ start,
                                               const uint2* __restrict__ erec,
                                               const u16* __restrict__ xb,
                                               const u16* __restrict__ ab,
                                               float* __restrict__ out) {
    int lane = threadIdx.x & 63;
    int node = blockIdx.x*4 + (threadIdx.x >> 6);
    int g = lane >> 4, l16 = lane & 15;

    const uint4* bn = (const uint4*)ab + (size_t)node*32;
    uint4 ar = bn[l16];
    uint4 br = bn[16 + l16];
    float arf[8], brf[8];
    {
        u32 aw[4] = {ar.x, ar.y, ar.z, ar.w};
        u32 bw[4] = {br.x, br.y, br.z, br.w};
        #pragma unroll
        for (int j = 0; j < 4; ++j) {
            arf[2*j]   = b2f_lo(aw[j]);
            arf[2*j+1] = b2f_hi(aw[j]);
            brf[2*j]   = b2f_lo(bw[j]);
            brf[2*j+1] = b2f_hi(bw[j]);
        }
    }
    u32 s0 = start[node];
    u32 n  = start[node+1] - s0;
    float vq_r = vsq[node];

    float accv[8];
    #pragma unroll
    for (int k = 0; k < 8; ++k) accv[k] = 0.f;
    float sphi = 0.f, wsum = 0.f;

    auto proc = [&](uint4 xc, float vqc, float w) {
        u32 xw[4] = {xc.x, xc.y, xc.z, xc.w};
        float xf[8];
        #pragma unroll
        for (int j = 0; j < 4; ++j) {
            xf[2*j]   = b2f_lo(xw[j]);
            xf[2*j+1] = b2f_hi(xw[j]);
        }
        float adot = 0.f, bdot = 0.f;
        #pragma unroll
        for (int j = 0; j < 8; ++j) {
            adot = fmaf(arf[j], xf[j], adot);
            bdot = fmaf(brf[j], xf[j], bdot);
        }
        #pragma unroll
        for (int mask = 1; mask < 16; mask <<= 1) {
            adot += __shfl_xor(adot, mask);
            bdot += __shfl_xor(bdot, mask);
        }
        float ss = fmaxf(vq_r + vqc - 2.f*bdot, 0.f);
        float psi = w * tanh_pos(fabsf(adot)) * tanh_pos(__fdividef(1.f, sqrtf(ss) + EPSF));
        sphi += psi;
        wsum += w;
        #pragma unroll
        for (int j = 0; j < 8; ++j)
            accv[j] = fmaf(psi, xf[j], accv[j]);
    };

    u32 p = g;
    for (; p + 4 < n; p += 8) {
        u32 i0 = s0 + p, i1 = s0 + p + 4;
        uint2 r0 = erec[i0], r1 = erec[i1];
        uint4 xc0 = ((const uint4*)xb)[(size_t)r0.x*16 + l16];
        uint4 xc1 = ((const uint4*)xb)[(size_t)r1.x*16 + l16];
        float vq0 = vsq[r0.x], vq1 = vsq[r1.x];
        proc(xc0, vq0, __uint_as_float(r0.y));
        proc(xc1, vq1, __uint_as_float(r1.y));
    }
    if (p < n) {
        u32 i0 = s0 + p;
        uint2 r0 = erec[i0];
        uint4 xc0 = ((const uint4*)xb)[(size_t)r0.x*16 + l16];
        proc(xc0, vsq[r0.x], __uint_as_float(r0.y));
    }

    // reduce across the 4 edge-groups
    #pragma unroll
    for (int mask = 16; mask < 64; mask <<= 1) {
        sphi += __shfl_xor(sphi, mask);
        wsum += __shfl_xor(wsum, mask);
        #pragma unroll
        for (int k = 0; k < 8; ++k) accv[k] += __shfl_xor(accv[k], mask);
    }

    float ia = (n == 0) ? 0.f : __fdividef(1.f, wsum * phichi[node]);

    if (g == 0) {
        float scale = 1.f - ia * sphi;
        const float* xp = x + (size_t)node*DD + l16*8;
        float xv[8];
        *(float4*)&xv[0] = ((const float4*)xp)[0];
        *(float4*)&xv[4] = ((const float4*)xp)[1];
        float4 o0, o1;
        o0.x = xv[0]*scale + ia*accv[0];
        o0.y = xv[1]*scale + ia*accv[1];
        o0.z = xv[2]*scale + ia*accv[2];
        o0.w = xv[3]*scale + ia*accv[3];
        o1.x = xv[4]*scale + ia*accv[4];
        o1.y = xv[5]*scale + ia*accv[5];
        o1.z = xv[6]*scale + ia*accv[6];
        o1.w = xv[7]*scale + ia*accv[7];
        float* po = out + (size_t)node*DD + l16*8;
        ((float4*)po)[0] = o0;
        ((float4*)po)[1] = o1;
    }
}

extern "C" void kernel_launch(void* const* d_in, const int* in_sizes, int n_in,
                              void* d_out, int out_size, void* d_ws, size_t ws_size,
                              hipStream_t stream) {
    const float* x     = (const float*)d_in[0];
    const int*   ei    = (const int*)d_in[1];
    const float* ew    = (const float*)d_in[2];
    const float* Wchi  = (const float*)d_in[3];
    const float* Wphi  = (const float*)d_in[4];
    const float* Wvphi = (const float*)d_in[5];
    float* out = (float*)d_out;
    float* ws  = (float*)d_ws;
    char*  wsb = (char*)d_ws;

    float* phichi = (float*)(wsb + OFF_PHICHI);
    float* vsq    = (float*)(wsb + OFF_VSQ);
    u32*   cnt    = (u32*)  (wsb + OFF_CNT);
    u32*   cursor = (u32*)  (wsb + OFF_CNT);    // alias: cnt dead after scans
    u32*   start  = (u32*)  (wsb + OFF_START);
    u32*   bsum   = (u32*)  (wsb + OFF_BSUM);
    u32*   boff   = (u32*)  (wsb + OFF_BOFF);
    u16*   ab     = (u16*)  (wsb + OFF_AB);
    u16*   xb     = (u16*)  (wsb + OFF_XB);
    uint2* erec   = (uint2*)(wsb + OFF_EREC);
    float* wcomb  = (float*)(wsb + OFF_WCOMB);  // temp, overlays erec
    u32*   rank   = (u32*)  (wsb + OFF_RANK);

    bool use_rank = (ws_size >= (size_t)WS_NEED_RANK);

    hipMemsetAsync(wsb + OFF_CNT, 0, 200000, stream);
    if (use_rank) {
        k_prep<true><<<dim3(HB+IB+WB), dim3(256), 0, stream>>>(ei, x, Wchi, ws, cnt, xb, rank);
    } else {
        k_prep<false><<<dim3(HB+IB+WB), dim3(256), 0, stream>>>(ei, x, Wchi, ws, cnt, xb, rank);
    }
    k_w1<<<dim3(128), dim3(256), 0, stream>>>(Wchi, Wphi, Wvphi, wcomb, ws);
    k_w2<<<dim3(64), dim3(256), 0, stream>>>(wcomb, ws);
    k_scan_bsum<<<dim3(NB_SCAN), dim3(256), 0, stream>>>(cnt, bsum);
    k_scan_boff<<<dim3(1), dim3(256), 0, stream>>>(bsum, boff);
    k_scan_final<<<dim3(NB_SCAN), dim3(256), 0, stream>>>(cnt, boff, start, cursor);
    if (use_rank) {
        k_mid<true><<<dim3(SB+NBLK), dim3(256), 0, stream>>>(ei, ew, start, cursor, rank, erec, x, ws, ab);
    } else {
        k_mid<false><<<dim3(SB+NBLK), dim3(256), 0, stream>>>(ei, ew, start, cursor, rank, erec, x, ws, ab);
    }
    k_accum<<<dim3(NNODES/4), dim3(256), 0, stream>>>(x, phichi, vsq, start, erec, xb, ab, out);
}

// Round 3
// 274.429 us; speedup vs baseline: 1.7139x; 1.0907x over previous
//
#include <hip/hip_runtime.h>
#include <hip/hip_bf16.h>

#define NNODES 50000
#define NEDGES 1600000
#define DD 128
#define EPSF 1e-6f
#define NB_SCAN 196   // ceil(50000/256)

using u32 = unsigned int;
using u16 = unsigned short;
using u64 = unsigned long long;
typedef __attribute__((ext_vector_type(8))) short v8s;   // 8 x bf16 (4 VGPR)
typedef __attribute__((ext_vector_type(4))) float v4f;   // mfma accumulator

static __device__ __forceinline__ float b2f_lo(u32 w) { return __uint_as_float(w << 16); }
static __device__ __forceinline__ float b2f_hi(u32 w) { return __uint_as_float(w & 0xffff0000u); }
static __device__ __forceinline__ float b2f16(u16 v) { return __uint_as_float(((u32)v) << 16); }
static __device__ __forceinline__ u16 f2b(float f) {
    u32 u = __float_as_uint(f);
    return (u16)((u + 0x7fffu + ((u >> 16) & 1u)) >> 16);
}
static __device__ __forceinline__ float tanh_pos(float a) {   // a >= 0, fast
    float e = __expf(-2.f * a);
    return __fdividef(1.f - e, 1.f + e);
}

// workspace byte offsets
#define OFF_GFRAG  0          // 3 * 32KB bf16 Gram matrices in MFMA B-frag layout
                              // mat 0 = Wcomb^T Wcomb, 1 = Wvphi^T Wvphi, 2 = Wchi^T Wchi
#define OFF_PHICHI 98304      // 50000 f32
#define OFF_VSQ    298304     // 50000 f32   x^T B x per node
#define OFF_CNT    498304     // 50000 u32   (aliased as cursor in fallback path)
#define OFF_START  698304     // 50001 u32
#define OFF_BSUM   898320     // 196 u32 (800 B)
#define OFF_BOFF   899120     // 196 u32 (800 B)
#define OFF_AB     899920     // 50000*256 u16 : per node [a 128][b 128] bf16 (512B rec)
#define OFF_XB     26499920   // 50000*128 u16 : x bf16 (256B rec)
#define OFF_EREC   39299920   // 1.6M uint2 (col, ew)
#define OFF_WCOMB  39299920   // 128*128 f32 TEMP, overlays EREC (dead before k_mid)
#define OFF_RANK   52099920   // 1.6M u32 rank-within-row -> ends 58,499,920
#define WS_NEED_RANK 58499920ull

// store val=G[a][c] into MFMA B-fragment layout for mfma_f32_16x16x32_bf16:
// lane = ((a>>3)&3)*16 + (c&15), j = a&7, frag = (mat*8 + c/16)*4 + a/32
static __device__ __forceinline__ void gstore(u16* gf, int mat, int a, int c, float v) {
    int lane = (((a >> 3) & 3) << 4) | (c & 15);
    int u = ((((mat*8 + (c >> 4))*4 + (a >> 5))*64 + lane) << 3) | (a & 7);
    gf[u] = f2b(v);
}

#define HB (NEDGES/256)       // 6250 hist blocks
#define IB (NNODES*DD/4/256)  // 6250 init blocks

template<bool RANK>
__global__ __launch_bounds__(256) void k_prep(const int* __restrict__ ei,
                                              const float* __restrict__ x,
                                              u32* __restrict__ cnt,
                                              u16* __restrict__ xb,
                                              u32* __restrict__ rank) {
    int b = blockIdx.x, t = threadIdx.x;
    if (b < HB) {                                  // histogram (+ per-edge rank)
        int e = b*256 + t;
        if (RANK) rank[e] = atomicAdd(&cnt[ei[e]], 1u);
        else      atomicAdd(&cnt[ei[e]], 1u);
    } else {                                       // x -> bf16 xb
        int idx = (b - HB)*256 + t;
        float4 v = ((const float4*)x)[idx];
        int n  = idx >> 5;
        int d4 = idx & 31;
        u32 p0 = (u32)f2b(v.x) | ((u32)f2b(v.y) << 16);
        u32 p1 = (u32)f2b(v.z) | ((u32)f2b(v.w) << 16);
        *(uint2*)(xb + (size_t)n*128 + d4*4) = make_uint2(p0, p1);
    }
}

// 192 blocks: b<64 -> Wcomb = Wphi@Wchi (fp32 temp);
//             b<128 -> Bgram = Wvphi^T Wvphi -> frag mat 1
//             else  -> Cgram = Wchi^T Wchi   -> frag mat 2
__global__ __launch_bounds__(256) void k_w1(const float* __restrict__ Wchi,
                                            const float* __restrict__ Wphi,
                                            const float* __restrict__ Wvphi,
                                            float* __restrict__ wcomb,
                                            u16* __restrict__ gf) {
    int b = blockIdx.x, t = threadIdx.x;
    if (b < 64) {
        int idx = b*256 + t;
        int i = idx >> 7, k = idx & 127;
        float acc = 0.f;
        #pragma unroll 8
        for (int m = 0; m < DD; ++m)
            acc = fmaf(Wphi[i*DD+m], Wchi[m*DD+k], acc);
        wcomb[i*DD+k] = acc;
    } else {
        const float* W = (b < 128) ? Wvphi : Wchi;
        int mat = (b < 128) ? 1 : 2;
        int idx = ((b & 63))*256 + t;
        int a = idx >> 7, c = idx & 127;
        float acc = 0.f;
        #pragma unroll 8
        for (int m = 0; m < DD; ++m)
            acc = fmaf(W[m*DD+a], W[m*DD+c], acc);
        gstore(gf, mat, a, c, acc);
    }
}

// grid NB_SCAN + 64: first NB_SCAN blocks do the per-block degree sums;
// blocks >= NB_SCAN compute Agram = Wcomb^T Wcomb -> frag mat 0
__global__ __launch_bounds__(256) void k_scan_bsum(const u32* __restrict__ cnt,
                                                   u32* __restrict__ bsum,
                                                   const float* __restrict__ wcomb,
                                                   u16* __restrict__ gf) {
    if (blockIdx.x >= NB_SCAN) {
        int idx = (blockIdx.x - NB_SCAN)*256 + threadIdx.x;
        int a = idx >> 7, c = idx & 127;
        float acc = 0.f;
        #pragma unroll 8
        for (int m = 0; m < DD; ++m)
            acc = fmaf(wcomb[m*DD+a], wcomb[m*DD+c], acc);
        gstore(gf, 0, a, c, acc);
        return;
    }
    __shared__ u32 s[256];
    int i = blockIdx.x*256 + threadIdx.x;
    s[threadIdx.x] = (i < NNODES) ? cnt[i] : 0u;
    __syncthreads();
    for (int off = 128; off > 0; off >>= 1) {
        if (threadIdx.x < off) s[threadIdx.x] += s[threadIdx.x + off];
        __syncthreads();
    }
    if (threadIdx.x == 0) bsum[blockIdx.x] = s[0];
}

__global__ __launch_bounds__(256) void k_scan_boff(const u32* __restrict__ bsum,
                                                   u32* __restrict__ boff) {
    __shared__ u32 s[256];
    int t = threadIdx.x;
    u32 v = (t < NB_SCAN) ? bsum[t] : 0u;
    s[t] = v;
    __syncthreads();
    for (int off = 1; off < 256; off <<= 1) {
        u32 a = (t >= off) ? s[t - off] : 0u;
        __syncthreads();
        s[t] += a;
        __syncthreads();
    }
    if (t < NB_SCAN) boff[t] = s[t] - v;           // exclusive
}

__global__ __launch_bounds__(256) void k_scan_final(const u32* __restrict__ cnt,
                                                    const u32* __restrict__ boff,
                                                    u32* __restrict__ start,
                                                    u32* __restrict__ cursor) {
    __shared__ u32 s[256];
    int t = threadIdx.x;
    int i = blockIdx.x*256 + t;
    u32 v = (i < NNODES) ? cnt[i] : 0u;
    s[t] = v;
    __syncthreads();
    for (int off = 1; off < 256; off <<= 1) {
        u32 a = (t >= off) ? s[t - off] : 0u;
        __syncthreads();
        s[t] += a;
        __syncthreads();
    }
    if (i < NNODES) {
        u32 val = boff[blockIdx.x] + (s[t] - v);
        start[i]  = val;
        cursor[i] = val;
        if (i == NNODES-1) start[NNODES] = val + v;
    }
}

#define SB (NEDGES/256)       // 6250 scatter blocks
#define GB 782                // gemm blocks: 64 nodes each (last partial)
// grid = SB + GB = 7032; b%9==0 -> gemm (782 exactly), else scatter

template<bool RANK>
__global__ __launch_bounds__(256) void k_mid(const int* __restrict__ ei,
                                             const float* __restrict__ ew,
                                             const u32* __restrict__ start,
                                             u32* __restrict__ cursor,
                                             const u32* __restrict__ rank,
                                             uint2* __restrict__ erec,
                                             const u16* __restrict__ xb,
                                             float* __restrict__ ws,
                                             u16* __restrict__ ab) {
    int b = blockIdx.x, t = threadIdx.x;
    if (b % 9 != 0) {                              // scatter into CSR (packed 8B record)
        int eb = b - b/9 - 1;
        int e = eb*256 + t;
        int r = __builtin_nontemporal_load(&ei[e]);
        u32 pos;
        if (RANK) pos = start[r] + __builtin_nontemporal_load(&rank[e]);
        else      pos = atomicAdd(&cursor[r], 1u);
        u32 c  = (u32)__builtin_nontemporal_load(&ei[NEDGES + e]);
        u32 wb = __float_as_uint(__builtin_nontemporal_load(&ew[e]));
        u64 recv = (u64)c | ((u64)wb << 32);
        __builtin_nontemporal_store(recv, (u64*)&erec[pos]);
        return;
    }
    // gemm role: 4 independent waves, 16 nodes each, MFMA over the 3 Gram matrices
    __shared__ u16 xs[4][16][DD];
    int w = t >> 6, l = t & 63;
    int l15 = l & 15, lq = l >> 4;
    int nb = (b/9)*64 + w*16;
    if (nb >= NNODES) return;

    // A-fragments: lane holds x[nb+l15][kk*32 + lq*8 + j], j=0..7
    const v8s* xbv = (const v8s*)(xb + (size_t)(nb + l15)*DD);
    v8s af[4];
    #pragma unroll
    for (int kk = 0; kk < 4; ++kk) {
        af[kk] = xbv[kk*4 + lq];
        *(v8s*)&xs[w][l15][kk*32 + lq*8] = af[kk];
    }
    const v8s* gf = (const v8s*)ws;                // OFF_GFRAG = 0
    float* phichi = ws + OFF_PHICHI/4;
    float* vsq    = ws + OFF_VSQ/4;

    #pragma unroll
    for (int mat = 0; mat < 3; ++mat) {
        v4f acc[8];
        #pragma unroll
        for (int nt = 0; nt < 8; ++nt) acc[nt] = (v4f){0.f,0.f,0.f,0.f};
        #pragma unroll
        for (int kk = 0; kk < 4; ++kk)
            #pragma unroll
            for (int nt = 0; nt < 8; ++nt)
                acc[nt] = __builtin_amdgcn_mfma_f32_16x16x32_bf16(
                    af[kk], gf[((mat*8 + nt)*4 + kk)*64 + l], acc[nt], 0, 0, 0);
        // D[m][n]: m = lq*4 + r (node), n = nt*16 + l15 (dim)   [m89-verified C/D map]
        if (mat < 2) {                             // store a (mat0) / b (mat1) bf16
            int base = mat ? 128 : 0;
            #pragma unroll
            for (int nt = 0; nt < 8; ++nt)
                #pragma unroll
                for (int r = 0; r < 4; ++r)
                    ab[(size_t)(nb + lq*4 + r)*256 + base + nt*16 + l15] = f2b(acc[nt][r]);
        }
        if (mat >= 1) {                            // x . (G x): vsq (mat1), phichi (mat2)
            float p0 = 0.f, p1 = 0.f, p2 = 0.f, p3 = 0.f;
            #pragma unroll
            for (int nt = 0; nt < 8; ++nt) {
                int nn = nt*16 + l15;
                p0 = fmaf(b2f16(xs[w][lq*4+0][nn]), acc[nt][0], p0);
                p1 = fmaf(b2f16(xs[w][lq*4+1][nn]), acc[nt][1], p1);
                p2 = fmaf(b2f16(xs[w][lq*4+2][nn]), acc[nt][2], p2);
                p3 = fmaf(b2f16(xs[w][lq*4+3][nn]), acc[nt][3], p3);
            }
            #pragma unroll
            for (int mask = 1; mask < 16; mask <<= 1) {
                p0 += __shfl_xor(p0, mask);
                p1 += __shfl_xor(p1, mask);
                p2 += __shfl_xor(p2, mask);
                p3 += __shfl_xor(p3, mask);
            }
            if (l15 == 0) {
                int n0 = nb + lq*4;
                if (mat == 1) {
                    vsq[n0+0] = p0; vsq[n0+1] = p1; vsq[n0+2] = p2; vsq[n0+3] = p3;
                } else {
                    phichi[n0+0] = tanh_pos(sqrtf(fmaxf(p0, 0.f)));
                    phichi[n0+1] = tanh_pos(sqrtf(fmaxf(p1, 0.f)));
                    phichi[n0+2] = tanh_pos(sqrtf(fmaxf(p2, 0.f)));
                    phichi[n0+3] = tanh_pos(sqrtf(fmaxf(p3, 0.f)));
                }
            }
        }
    }
}

// one wave per node; 4 edges concurrently (16 lanes each); unroll 2
// per-edge gather: x_c (256B) + vsq_c (4B, L2-resident)
__global__ __launch_bounds__(256) void k_accum(const float* __restrict__ x,
                                               const float* __restrict__ phichi,
                                               const float* __restrict__ vsq,
                                               const u32* __restrict__ start,
                                               const uint2* __restrict__ erec,
                                               const u16* __restrict__ xb,
                                               const u16* __restrict__ ab,
                                               float* __restrict__ out) {
    int lane = threadIdx.x & 63;
    int node = blockIdx.x*4 + (threadIdx.x >> 6);
    int g = lane >> 4, l16 = lane & 15;

    const uint4* bn = (const uint4*)ab + (size_t)node*32;
    uint4 ar = bn[l16];
    uint4 br = bn[16 + l16];
    float arf[8], brf[8];
    {
        u32 aw[4] = {ar.x, ar.y, ar.z, ar.w};
        u32 bw[4] = {br.x, br.y, br.z, br.w};
        #pragma unroll
        for (int j = 0; j < 4; ++j) {
            arf[2*j]   = b2f_lo(aw[j]);
            arf[2*j+1] = b2f_hi(aw[j]);
            brf[2*j]   = b2f_lo(bw[j]);
            brf[2*j+1] = b2f_hi(bw[j]);
        }
    }
    u32 s0 = start[node];
    u32 n  = start[node+1] - s0;
    float vq_r = vsq[node];

    float accv[8];
    #pragma unroll
    for (int k = 0; k < 8; ++k) accv[k] = 0.f;
    float sphi = 0.f, wsum = 0.f;

    auto proc = [&](uint4 xc, float vqc, float w) {
        u32 xw[4] = {xc.x, xc.y, xc.z, xc.w};
        float xf[8];
        #pragma unroll
        for (int j = 0; j < 4; ++j) {
            xf[2*j]   = b2f_lo(xw[j]);
            xf[2*j+1] = b2f_hi(xw[j]);
        }
        float adot = 0.f, bdot = 0.f;
        #pragma unroll
        for (int j = 0; j < 8; ++j) {
            adot = fmaf(arf[j], xf[j], adot);
            bdot = fmaf(brf[j], xf[j], bdot);
        }
        #pragma unroll
        for (int mask = 1; mask < 16; mask <<= 1) {
            adot += __shfl_xor(adot, mask);
            bdot += __shfl_xor(bdot, mask);
        }
        float ss = fmaxf(vq_r + vqc - 2.f*bdot, 0.f);
        float psi = w * tanh_pos(fabsf(adot)) * tanh_pos(__fdividef(1.f, sqrtf(ss) + EPSF));
        sphi += psi;
        wsum += w;
        #pragma unroll
        for (int j = 0; j < 8; ++j)
            accv[j] = fmaf(psi, xf[j], accv[j]);
    };

    u32 p = g;
    for (; p + 4 < n; p += 8) {
        u32 i0 = s0 + p, i1 = s0 + p + 4;
        uint2 r0 = erec[i0], r1 = erec[i1];
        uint4 xc0 = ((const uint4*)xb)[(size_t)r0.x*16 + l16];
        uint4 xc1 = ((const uint4*)xb)[(size_t)r1.x*16 + l16];
        float vq0 = vsq[r0.x], vq1 = vsq[r1.x];
        proc(xc0, vq0, __uint_as_float(r0.y));
        proc(xc1, vq1, __uint_as_float(r1.y));
    }
    if (p < n) {
        u32 i0 = s0 + p;
        uint2 r0 = erec[i0];
        uint4 xc0 = ((const uint4*)xb)[(size_t)r0.x*16 + l16];
        proc(xc0, vsq[r0.x], __uint_as_float(r0.y));
    }

    // reduce across the 4 edge-groups
    #pragma unroll
    for (int mask = 16; mask < 64; mask <<= 1) {
        sphi += __shfl_xor(sphi, mask);
        wsum += __shfl_xor(wsum, mask);
        #pragma unroll
        for (int k = 0; k < 8; ++k) accv[k] += __shfl_xor(accv[k], mask);
    }

    float ia = (n == 0) ? 0.f : __fdividef(1.f, wsum * phichi[node]);

    if (g == 0) {
        float scale = 1.f - ia * sphi;
        const float* xp = x + (size_t)node*DD + l16*8;
        float xv[8];
        *(float4*)&xv[0] = ((const float4*)xp)[0];
        *(float4*)&xv[4] = ((const float4*)xp)[1];
        v4f o0, o1;
        o0.x = xv[0]*scale + ia*accv[0];
        o0.y = xv[1]*scale + ia*accv[1];
        o0.z = xv[2]*scale + ia*accv[2];
        o0.w = xv[3]*scale + ia*accv[3];
        o1.x = xv[4]*scale + ia*accv[4];
        o1.y = xv[5]*scale + ia*accv[5];
        o1.z = xv[6]*scale + ia*accv[6];
        o1.w = xv[7]*scale + ia*accv[7];
        float* po = out + (size_t)node*DD + l16*8;
        __builtin_nontemporal_store(o0, (v4f*)po);
        __builtin_nontemporal_store(o1, (v4f*)(po + 4));
    }
}

extern "C" void kernel_launch(void* const* d_in, const int* in_sizes, int n_in,
                              void* d_out, int out_size, void* d_ws, size_t ws_size,
                              hipStream_t stream) {
    const float* x     = (const float*)d_in[0];
    const int*   ei    = (const int*)d_in[1];
    const float* ew    = (const float*)d_in[2];
    const float* Wchi  = (const float*)d_in[3];
    const float* Wphi  = (const float*)d_in[4];
    const float* Wvphi = (const float*)d_in[5];
    float* out = (float*)d_out;
    float* ws  = (float*)d_ws;
    char*  wsb = (char*)d_ws;

    float* phichi = (float*)(wsb + OFF_PHICHI);
    float* vsq    = (float*)(wsb + OFF_VSQ);
    u32*   cnt    = (u32*)  (wsb + OFF_CNT);
    u32*   cursor = (u32*)  (wsb + OFF_CNT);    // alias: cnt dead after scans
    u32*   start  = (u32*)  (wsb + OFF_START);
    u32*   bsum   = (u32*)  (wsb + OFF_BSUM);
    u32*   boff   = (u32*)  (wsb + OFF_BOFF);
    u16*   gf     = (u16*)  (wsb + OFF_GFRAG);
    u16*   ab     = (u16*)  (wsb + OFF_AB);
    u16*   xb     = (u16*)  (wsb + OFF_XB);
    uint2* erec   = (uint2*)(wsb + OFF_EREC);
    float* wcomb  = (float*)(wsb + OFF_WCOMB);  // temp, overlays erec
    u32*   rank   = (u32*)  (wsb + OFF_RANK);

    bool use_rank = (ws_size >= (size_t)WS_NEED_RANK);

    hipMemsetAsync(wsb + OFF_CNT, 0, 200000, stream);
    if (use_rank) {
        k_prep<true><<<dim3(HB+IB), dim3(256), 0, stream>>>(ei, x, cnt, xb, rank);
    } else {
        k_prep<false><<<dim3(HB+IB), dim3(256), 0, stream>>>(ei, x, cnt, xb, rank);
    }
    k_w1<<<dim3(192), dim3(256), 0, stream>>>(Wchi, Wphi, Wvphi, wcomb, gf);
    k_scan_bsum<<<dim3(NB_SCAN+64), dim3(256), 0, stream>>>(cnt, bsum, wcomb, gf);
    k_scan_boff<<<dim3(1), dim3(256), 0, stream>>>(bsum, boff);
    k_scan_final<<<dim3(NB_SCAN), dim3(256), 0, stream>>>(cnt, boff, start, cursor);
    if (use_rank) {
        k_mid<true><<<dim3(SB+GB), dim3(256), 0, stream>>>(ei, ew, start, cursor, rank, erec, xb, ws, ab);
    } else {
        k_mid<false><<<dim3(SB+GB), dim3(256), 0, stream>>>(ei, ew, start, cursor, rank, erec, xb, ws, ab);
    }
    k_accum<<<dim3(NNODES/4), dim3(256), 0, stream>>>(x, phichi, vsq, start, erec, xb, ab, out);
}

// Round 5
// 262.162 us; speedup vs baseline: 1.7941x; 1.0468x over previous
//
#include <hip/hip_runtime.h>
#include <hip/hip_bf16.h>

#define NNODES 50000
#define NEDGES 1600000
#define DD 128
#define EPSF 1e-6f
#define NB_SCAN 196   // ceil(50000/256)

using u32 = unsigned int;
using u16 = unsigned short;
using u64 = unsigned long long;
typedef __attribute__((ext_vector_type(8))) short v8s;   // 8 x bf16 (4 VGPR)
typedef __attribute__((ext_vector_type(4))) float v4f;   // mfma accumulator
typedef __attribute__((ext_vector_type(2))) float v2f;   // nontemporal-storable pair

static __device__ __forceinline__ float b2f_lo(u32 w) { return __uint_as_float(w << 16); }
static __device__ __forceinline__ float b2f_hi(u32 w) { return __uint_as_float(w & 0xffff0000u); }
static __device__ __forceinline__ float b2f16(u16 v) { return __uint_as_float(((u32)v) << 16); }
static __device__ __forceinline__ u16 f2b(float f) {
    u32 u = __float_as_uint(f);
    return (u16)((u + 0x7fffu + ((u >> 16) & 1u)) >> 16);
}
static __device__ __forceinline__ float tanh_pos(float a) {   // a >= 0, fast
    float e = __expf(-2.f * a);
    return __fdividef(1.f - e, 1.f + e);
}

// workspace byte offsets
#define OFF_GFRAG  0          // 3 * 32KB bf16 Gram matrices in MFMA B-frag layout
                              // mat 0 = Wcomb^T Wcomb, 1 = Wvphi^T Wvphi, 2 = Wchi^T Wchi
#define OFF_PHICHI 98304      // 50000 f32
#define OFF_VSQ    298304     // 50000 f32   x^T B x per node
#define OFF_CNT    498304     // 50000 u32   (aliased as cursor in fallback path)
#define OFF_START  698304     // 50001 u32
#define OFF_BSUM   898320     // 196 u32 (800 B)
#define OFF_BOFF   899120     // 196 u32 (800 B)
#define OFF_AB     899920     // 50000*256 u16 : per node [a 128][b 128] bf16 (512B rec)
#define OFF_XB     26499920   // 50000*128 u16 : x bf16 (256B rec)
#define OFF_EREC   39299920   // 1.6M uint2 (col, ew)
#define OFF_WCOMB  39299920   // 128*128 f32 TEMP, overlays EREC (dead before k_mid)
#define OFF_RANK   52099920   // 1.6M u32 rank-within-row -> ends 58,499,920
#define WS_NEED_RANK 58499920ull

// store val=G[a][c] into MFMA B-fragment layout for mfma_f32_16x16x32_bf16:
// lane = ((a>>3)&3)*16 + (c&15), j = a&7, frag = (mat*8 + c/16)*4 + a/32
static __device__ __forceinline__ void gstore(u16* gf, int mat, int a, int c, float v) {
    int lane = (((a >> 3) & 3) << 4) | (c & 15);
    int u = ((((mat*8 + (c >> 4))*4 + (a >> 5))*64 + lane) << 3) | (a & 7);
    gf[u] = f2b(v);
}

#define HB (NEDGES/256)       // 6250 hist blocks
#define IB (NNODES*DD/4/256)  // 6250 init blocks

template<bool RANK>
__global__ __launch_bounds__(256) void k_prep(const int* __restrict__ ei,
                                              const float* __restrict__ x,
                                              u32* __restrict__ cnt,
                                              u16* __restrict__ xb,
                                              u32* __restrict__ rank) {
    int b = blockIdx.x, t = threadIdx.x;
    if (b < HB) {                                  // histogram (+ per-edge rank)
        int e = b*256 + t;
        if (RANK) rank[e] = atomicAdd(&cnt[ei[e]], 1u);
        else      atomicAdd(&cnt[ei[e]], 1u);
    } else {                                       // x -> bf16 xb
        int idx = (b - HB)*256 + t;
        float4 v = ((const float4*)x)[idx];
        int n  = idx >> 5;
        int d4 = idx & 31;
        u32 p0 = (u32)f2b(v.x) | ((u32)f2b(v.y) << 16);
        u32 p1 = (u32)f2b(v.z) | ((u32)f2b(v.w) << 16);
        *(uint2*)(xb + (size_t)n*128 + d4*4) = make_uint2(p0, p1);
    }
}

// 192 blocks: b<64 -> Wcomb = Wphi@Wchi (fp32 temp);
//             b<128 -> Bgram = Wvphi^T Wvphi -> frag mat 1
//             else  -> Cgram = Wchi^T Wchi   -> frag mat 2
__global__ __launch_bounds__(256) void k_w1(const float* __restrict__ Wchi,
                                            const float* __restrict__ Wphi,
                                            const float* __restrict__ Wvphi,
                                            float* __restrict__ wcomb,
                                            u16* __restrict__ gf) {
    int b = blockIdx.x, t = threadIdx.x;
    if (b < 64) {
        int idx = b*256 + t;
        int i = idx >> 7, k = idx & 127;
        float acc = 0.f;
        #pragma unroll 8
        for (int m = 0; m < DD; ++m)
            acc = fmaf(Wphi[i*DD+m], Wchi[m*DD+k], acc);
        wcomb[i*DD+k] = acc;
    } else {
        const float* W = (b < 128) ? Wvphi : Wchi;
        int mat = (b < 128) ? 1 : 2;
        int idx = ((b & 63))*256 + t;
        int a = idx >> 7, c = idx & 127;
        float acc = 0.f;
        #pragma unroll 8
        for (int m = 0; m < DD; ++m)
            acc = fmaf(W[m*DD+a], W[m*DD+c], acc);
        gstore(gf, mat, a, c, acc);
    }
}

// grid NB_SCAN + 64: first NB_SCAN blocks do the per-block degree sums;
// blocks >= NB_SCAN compute Agram = Wcomb^T Wcomb -> frag mat 0
__global__ __launch_bounds__(256) void k_scan_bsum(const u32* __restrict__ cnt,
                                                   u32* __restrict__ bsum,
                                                   const float* __restrict__ wcomb,
                                                   u16* __restrict__ gf) {
    if (blockIdx.x >= NB_SCAN) {
        int idx = (blockIdx.x - NB_SCAN)*256 + threadIdx.x;
        int a = idx >> 7, c = idx & 127;
        float acc = 0.f;
        #pragma unroll 8
        for (int m = 0; m < DD; ++m)
            acc = fmaf(wcomb[m*DD+a], wcomb[m*DD+c], acc);
        gstore(gf, 0, a, c, acc);
        return;
    }
    __shared__ u32 s[256];
    int i = blockIdx.x*256 + threadIdx.x;
    s[threadIdx.x] = (i < NNODES) ? cnt[i] : 0u;
    __syncthreads();
    for (int off = 128; off > 0; off >>= 1) {
        if (threadIdx.x < off) s[threadIdx.x] += s[threadIdx.x + off];
        __syncthreads();
    }
    if (threadIdx.x == 0) bsum[blockIdx.x] = s[0];
}

__global__ __launch_bounds__(256) void k_scan_boff(const u32* __restrict__ bsum,
                                                   u32* __restrict__ boff) {
    __shared__ u32 s[256];
    int t = threadIdx.x;
    u32 v = (t < NB_SCAN) ? bsum[t] : 0u;
    s[t] = v;
    __syncthreads();
    for (int off = 1; off < 256; off <<= 1) {
        u32 a = (t >= off) ? s[t - off] : 0u;
        __syncthreads();
        s[t] += a;
        __syncthreads();
    }
    if (t < NB_SCAN) boff[t] = s[t] - v;           // exclusive
}

__global__ __launch_bounds__(256) void k_scan_final(const u32* __restrict__ cnt,
                                                    const u32* __restrict__ boff,
                                                    u32* __restrict__ start,
                                                    u32* __restrict__ cursor) {
    __shared__ u32 s[256];
    int t = threadIdx.x;
    int i = blockIdx.x*256 + t;
    u32 v = (i < NNODES) ? cnt[i] : 0u;
    s[t] = v;
    __syncthreads();
    for (int off = 1; off < 256; off <<= 1) {
        u32 a = (t >= off) ? s[t - off] : 0u;
        __syncthreads();
        s[t] += a;
        __syncthreads();
    }
    if (i < NNODES) {
        u32 val = boff[blockIdx.x] + (s[t] - v);
        start[i]  = val;
        cursor[i] = val;
        if (i == NNODES-1) start[NNODES] = val + v;
    }
}

#define SB (NEDGES/256)       // 6250 scatter blocks
#define GB 782                // gemm blocks: 64 nodes each (last partial)
// grid = SB + GB = 7032; b%9==0 -> gemm (782 exactly), else scatter

template<bool RANK>
__global__ __launch_bounds__(256) void k_mid(const int* __restrict__ ei,
                                             const float* __restrict__ ew,
                                             const u32* __restrict__ start,
                                             u32* __restrict__ cursor,
                                             const u32* __restrict__ rank,
                                             uint2* __restrict__ erec,
                                             const u16* __restrict__ xb,
                                             float* __restrict__ ws,
                                             u16* __restrict__ ab) {
    int b = blockIdx.x, t = threadIdx.x;
    if (b % 9 != 0) {                              // scatter into CSR (packed 8B record)
        int eb = b - b/9 - 1;
        int e = eb*256 + t;
        int r = __builtin_nontemporal_load(&ei[e]);
        u32 pos;
        if (RANK) pos = start[r] + __builtin_nontemporal_load(&rank[e]);
        else      pos = atomicAdd(&cursor[r], 1u);
        u32 c  = (u32)__builtin_nontemporal_load(&ei[NEDGES + e]);
        u32 wb = __float_as_uint(__builtin_nontemporal_load(&ew[e]));
        u64 recv = (u64)c | ((u64)wb << 32);
        __builtin_nontemporal_store(recv, (u64*)&erec[pos]);
        return;
    }
    // gemm role: 4 independent waves, 16 nodes each, MFMA over the 3 Gram matrices
    __shared__ u16 xs[4][16][DD];
    int w = t >> 6, l = t & 63;
    int l15 = l & 15, lq = l >> 4;
    int nb = (b/9)*64 + w*16;
    if (nb >= NNODES) return;

    // A-fragments: lane holds x[nb+l15][kk*32 + lq*8 + j], j=0..7
    const v8s* xbv = (const v8s*)(xb + (size_t)(nb + l15)*DD);
    v8s af[4];
    #pragma unroll
    for (int kk = 0; kk < 4; ++kk) {
        af[kk] = xbv[kk*4 + lq];
        *(v8s*)&xs[w][l15][kk*32 + lq*8] = af[kk];
    }
    const v8s* gf = (const v8s*)ws;                // OFF_GFRAG = 0
    float* phichi = ws + OFF_PHICHI/4;
    float* vsq    = ws + OFF_VSQ/4;

    #pragma unroll
    for (int mat = 0; mat < 3; ++mat) {
        v4f acc[8];
        #pragma unroll
        for (int nt = 0; nt < 8; ++nt) acc[nt] = (v4f){0.f,0.f,0.f,0.f};
        #pragma unroll
        for (int kk = 0; kk < 4; ++kk)
            #pragma unroll
            for (int nt = 0; nt < 8; ++nt)
                acc[nt] = __builtin_amdgcn_mfma_f32_16x16x32_bf16(
                    af[kk], gf[((mat*8 + nt)*4 + kk)*64 + l], acc[nt], 0, 0, 0);
        // D[m][n]: m = lq*4 + r (node), n = nt*16 + l15 (dim)   [m89-verified C/D map]
        if (mat < 2) {                             // store a (mat0) / b (mat1) bf16
            int base = mat ? 128 : 0;
            #pragma unroll
            for (int nt = 0; nt < 8; ++nt)
                #pragma unroll
                for (int r = 0; r < 4; ++r)
                    ab[(size_t)(nb + lq*4 + r)*256 + base + nt*16 + l15] = f2b(acc[nt][r]);
        }
        if (mat >= 1) {                            // x . (G x): vsq (mat1), phichi (mat2)
            float p0 = 0.f, p1 = 0.f, p2 = 0.f, p3 = 0.f;
            #pragma unroll
            for (int nt = 0; nt < 8; ++nt) {
                int nn = nt*16 + l15;
                p0 = fmaf(b2f16(xs[w][lq*4+0][nn]), acc[nt][0], p0);
                p1 = fmaf(b2f16(xs[w][lq*4+1][nn]), acc[nt][1], p1);
                p2 = fmaf(b2f16(xs[w][lq*4+2][nn]), acc[nt][2], p2);
                p3 = fmaf(b2f16(xs[w][lq*4+3][nn]), acc[nt][3], p3);
            }
            #pragma unroll
            for (int mask = 1; mask < 16; mask <<= 1) {
                p0 += __shfl_xor(p0, mask);
                p1 += __shfl_xor(p1, mask);
                p2 += __shfl_xor(p2, mask);
                p3 += __shfl_xor(p3, mask);
            }
            if (l15 == 0) {
                int n0 = nb + lq*4;
                if (mat == 1) {
                    vsq[n0+0] = p0; vsq[n0+1] = p1; vsq[n0+2] = p2; vsq[n0+3] = p3;
                } else {
                    phichi[n0+0] = tanh_pos(sqrtf(fmaxf(p0, 0.f)));
                    phichi[n0+1] = tanh_pos(sqrtf(fmaxf(p1, 0.f)));
                    phichi[n0+2] = tanh_pos(sqrtf(fmaxf(p2, 0.f)));
                    phichi[n0+3] = tanh_pos(sqrtf(fmaxf(p3, 0.f)));
                }
            }
        }
    }
}

// one wave per node; 16 edges per MFMA tile.
// A rows: 0 = a_r, 1 = b_r (bf16 from ab), rows 2-15 zero.
// B cols: 16 gathered x_c. D row=lq*4+reg, col=l15 (R2/R3-validated maps).
__global__ __launch_bounds__(256) void k_accum(const float* __restrict__ x,
                                               const float* __restrict__ phichi,
                                               const float* __restrict__ vsq,
                                               const u32* __restrict__ start,
                                               const uint2* __restrict__ erec,
                                               const u16* __restrict__ xb,
                                               const u16* __restrict__ ab,
                                               float* __restrict__ out) {
    __shared__ float red[4][16][132];              // per-wave transpose-reduce (+4 pad)
    int w = threadIdx.x >> 6, lane = threadIdx.x & 63;
    int node = blockIdx.x*4 + w;
    int l15 = lane & 15, lq = lane >> 4;

    u32 s0 = start[node];
    u32 n  = start[node+1] - s0;
    float vq_r = vsq[node];

    // A fragments: row l15==0 -> a_r slice, row l15==1 -> b_r slice, else 0
    v8s zero = {0,0,0,0,0,0,0,0};
    v8s afr[4];
    {
        const v8s* abv = (const v8s*)(ab + (size_t)node*256 + ((l15 == 1) ? 128 : 0));
        bool keep = (l15 < 2);
        #pragma unroll
        for (int kk = 0; kk < 4; ++kk) {
            v8s v = abv[kk*4 + lq];
            afr[kk] = keep ? v : zero;
        }
    }

    float accl[4][8];                              // per-lane accv partial, frag layout
    #pragma unroll
    for (int kk = 0; kk < 4; ++kk)
        #pragma unroll
        for (int j = 0; j < 8; ++j) accl[kk][j] = 0.f;
    float sphi = 0.f, wsum = 0.f;

    u32 ntiles = (n + 15) >> 4;

    auto tile = [&](u32 tt) {
        u32 off = tt*16 + (u32)l15;
        bool valid = off < n;
        u32 eidx = valid ? (s0 + off) : s0;        // clamp: safe, masked below
        uint2 r = erec[eidx];
        u32 c = r.x;
        float w_e = valid ? __uint_as_float(r.y) : 0.f;
        float vqc = vsq[c];
        const v8s* xcv = (const v8s*)(xb + (size_t)c*128);
        v8s bfr[4];
        #pragma unroll
        for (int kk = 0; kk < 4; ++kk) bfr[kk] = xcv[kk*4 + lq];

        v4f d = {0.f, 0.f, 0.f, 0.f};
        #pragma unroll
        for (int kk = 0; kk < 4; ++kk)
            d = __builtin_amdgcn_mfma_f32_16x16x32_bf16(afr[kk], bfr[kk], d, 0, 0, 0);
        // lq==0 lanes: d[0]=adot(edge l15), d[1]=bdot; other lanes: exact 0 (zero A rows)
        float ss = fmaxf(vq_r + vqc - 2.f*d[1], 0.f);
        float psi = w_e * tanh_pos(fabsf(d[0])) * tanh_pos(__fdividef(1.f, sqrtf(ss) + EPSF));
        float psi_b = __shfl(psi, l15);            // broadcast edge l15's psi to all lq
        sphi += psi_b;
        wsum += w_e;
        #pragma unroll
        for (int kk = 0; kk < 4; ++kk) {
            u32* pw = (u32*)&bfr[kk];
            #pragma unroll
            for (int q = 0; q < 4; ++q) {
                accl[kk][2*q]   = fmaf(psi_b, b2f_lo(pw[q]), accl[kk][2*q]);
                accl[kk][2*q+1] = fmaf(psi_b, b2f_hi(pw[q]), accl[kk][2*q+1]);
            }
        }
    };

    u32 tt = 0;
    for (; tt + 1 < ntiles; tt += 2) { tile(tt); tile(tt + 1); }
    if (tt < ntiles) tile(tt);

    // reduce sphi/wsum over the 16 edge-slots (lq copies identical afterwards)
    #pragma unroll
    for (int mask = 1; mask < 16; mask <<= 1) {
        sphi += __shfl_xor(sphi, mask);
        wsum += __shfl_xor(wsum, mask);
    }

    // accv: LDS transpose-reduce. lane holds dims {kk*32+lq*8+j} for edge-slot l15
    #pragma unroll
    for (int kk = 0; kk < 4; ++kk) {
        *(float4*)&red[w][l15][kk*32 + lq*8]     = *(float4*)&accl[kk][0];
        *(float4*)&red[w][l15][kk*32 + lq*8 + 4] = *(float4*)&accl[kk][4];
    }
    __syncthreads();
    float a0 = 0.f, a1 = 0.f;
    #pragma unroll
    for (int e = 0; e < 16; ++e) {
        float2 v = *(const float2*)&red[w][e][lane*2];
        a0 += v.x; a1 += v.y;
    }

    float ia = (n == 0) ? 0.f : __fdividef(1.f, wsum * phichi[node]);
    float scale = 1.f - ia * sphi;
    float2 xv = *(const float2*)(x + (size_t)node*DD + lane*2);
    v2f o;
    o.x = xv.x*scale + ia*a0;
    o.y = xv.y*scale + ia*a1;
    __builtin_nontemporal_store(o, (v2f*)(out + (size_t)node*DD + lane*2));
}

extern "C" void kernel_launch(void* const* d_in, const int* in_sizes, int n_in,
                              void* d_out, int out_size, void* d_ws, size_t ws_size,
                              hipStream_t stream) {
    const float* x     = (const float*)d_in[0];
    const int*   ei    = (const int*)d_in[1];
    const float* ew    = (const float*)d_in[2];
    const float* Wchi  = (const float*)d_in[3];
    const float* Wphi  = (const float*)d_in[4];
    const float* Wvphi = (const float*)d_in[5];
    float* out = (float*)d_out;
    float* ws  = (float*)d_ws;
    char*  wsb = (char*)d_ws;

    float* phichi = (float*)(wsb + OFF_PHICHI);
    float* vsq    = (float*)(wsb + OFF_VSQ);
    u32*   cnt    = (u32*)  (wsb + OFF_CNT);
    u32*   cursor = (u32*)  (wsb + OFF_CNT);    // alias: cnt dead after scans
    u32*   start  = (u32*)  (wsb + OFF_START);
    u32*   bsum   = (u32*)  (wsb + OFF_BSUM);
    u32*   boff   = (u32*)  (wsb + OFF_BOFF);
    u16*   gf     = (u16*)  (wsb + OFF_GFRAG);
    u16*   ab     = (u16*)  (wsb + OFF_AB);
    u16*   xb     = (u16*)  (wsb + OFF_XB);
    uint2* erec   = (uint2*)(wsb + OFF_EREC);
    float* wcomb  = (float*)(wsb + OFF_WCOMB);  // temp, overlays erec
    u32*   rank   = (u32*)  (wsb + OFF_RANK);

    bool use_rank = (ws_size >= (size_t)WS_NEED_RANK);

    hipMemsetAsync(wsb + OFF_CNT, 0, 200000, stream);
    if (use_rank) {
        k_prep<true><<<dim3(HB+IB), dim3(256), 0, stream>>>(ei, x, cnt, xb, rank);
    } else {
        k_prep<false><<<dim3(HB+IB), dim3(256), 0, stream>>>(ei, x, cnt, xb, rank);
    }
    k_w1<<<dim3(192), dim3(256), 0, stream>>>(Wchi, Wphi, Wvphi, wcomb, gf);
    k_scan_bsum<<<dim3(NB_SCAN+64), dim3(256), 0, stream>>>(cnt, bsum, wcomb, gf);
    k_scan_boff<<<dim3(1), dim3(256), 0, stream>>>(bsum, boff);
    k_scan_final<<<dim3(NB_SCAN), dim3(256), 0, stream>>>(cnt, boff, start, cursor);
    if (use_rank) {
        k_mid<true><<<dim3(SB+GB), dim3(256), 0, stream>>>(ei, ew, start, cursor, rank, erec, xb, ws, ab);
    } else {
        k_mid<false><<<dim3(SB+GB), dim3(256), 0, stream>>>(ei, ew, start, cursor, rank, erec, xb, ws, ab);
    }
    k_accum<<<dim3(NNODES/4), dim3(256), 0, stream>>>(x, phichi, vsq, start, erec, xb, ab, out);
}

// Round 6
// 261.811 us; speedup vs baseline: 1.7965x; 1.0013x over previous
//
#include <hip/hip_runtime.h>
#include <hip/hip_bf16.h>

#define NNODES 50000
#define NEDGES 1600000
#define DD 128
#define EPSF 1e-6f
#define NB_SCAN 196   // ceil(50000/256)

using u32 = unsigned int;
using u16 = unsigned short;
using u64 = unsigned long long;
typedef __attribute__((ext_vector_type(8))) short v8s;   // 8 x bf16 (4 VGPR)
typedef __attribute__((ext_vector_type(4))) float v4f;   // mfma accumulator
typedef __attribute__((ext_vector_type(2))) float v2f;   // nontemporal-storable pair

static __device__ __forceinline__ float b2f_lo(u32 w) { return __uint_as_float(w << 16); }
static __device__ __forceinline__ float b2f_hi(u32 w) { return __uint_as_float(w & 0xffff0000u); }
static __device__ __forceinline__ float b2f16(u16 v) { return __uint_as_float(((u32)v) << 16); }
static __device__ __forceinline__ u16 f2b(float f) {
    u32 u = __float_as_uint(f);
    return (u16)((u + 0x7fffu + ((u >> 16) & 1u)) >> 16);
}
static __device__ __forceinline__ float tanh_pos(float a) {   // a >= 0, fast
    float e = __expf(-2.f * a);
    return __fdividef(1.f - e, 1.f + e);
}

// workspace byte offsets
#define OFF_GFRAG  0          // 3 * 32KB bf16 Gram matrices in MFMA B-frag layout
                              // mat 0 = Wcomb^T Wcomb, 1 = Wvphi^T Wvphi, 2 = Wchi^T Wchi
#define OFF_PHICHI 98304      // 50000 f32
#define OFF_VSQ    298304     // 50000 f32   x^T B x per node
#define OFF_CNT    498304     // 50000 u32   (aliased as cursor in fallback path)
#define OFF_START  698304     // 50001 u32
#define OFF_BSUM   898320     // 196 u32 (800 B)
#define OFF_BOFF   899120     // 196 u32 (800 B)
#define OFF_AB     899920     // 50000*256 u16 : per node [a 128][b 128] bf16 (512B rec)
#define OFF_XB     26499920   // 50000*128 u16 : x bf16 (256B rec)
#define OFF_EREC   39299920   // 1.6M uint2 (col, ew)
#define OFF_WCOMB  39299920   // 128*128 f32 TEMP, overlays EREC (dead before k_mid)
#define OFF_RANK   52099920   // 1.6M u32 rank-within-row -> ends 58,499,920
#define WS_NEED_RANK 58499920ull

// store val=G[a][c] into MFMA B-fragment layout for mfma_f32_16x16x32_bf16:
// lane = ((a>>3)&3)*16 + (c&15), j = a&7, frag = (mat*8 + c/16)*4 + a/32
static __device__ __forceinline__ void gstore(u16* gf, int mat, int a, int c, float v) {
    int lane = (((a >> 3) & 3) << 4) | (c & 15);
    int u = ((((mat*8 + (c >> 4))*4 + (a >> 5))*64 + lane) << 3) | (a & 7);
    gf[u] = f2b(v);
}

#define HB (NEDGES/256)       // 6250 hist blocks
#define IB (NNODES*DD/4/256)  // 6250 init blocks

template<bool RANK>
__global__ __launch_bounds__(256) void k_prep(const int* __restrict__ ei,
                                              const float* __restrict__ x,
                                              u32* __restrict__ cnt,
                                              u16* __restrict__ xb,
                                              u32* __restrict__ rank) {
    int b = blockIdx.x, t = threadIdx.x;
    if (b < HB) {                                  // histogram (+ per-edge rank)
        int e = b*256 + t;
        if (RANK) rank[e] = atomicAdd(&cnt[ei[e]], 1u);
        else      atomicAdd(&cnt[ei[e]], 1u);
    } else {                                       // x -> bf16 xb
        int idx = (b - HB)*256 + t;
        float4 v = ((const float4*)x)[idx];
        int n  = idx >> 5;
        int d4 = idx & 31;
        u32 p0 = (u32)f2b(v.x) | ((u32)f2b(v.y) << 16);
        u32 p1 = (u32)f2b(v.z) | ((u32)f2b(v.w) << 16);
        *(uint2*)(xb + (size_t)n*128 + d4*4) = make_uint2(p0, p1);
    }
}

// 192 blocks: b<64 -> Wcomb = Wphi@Wchi (fp32 temp);
//             b<128 -> Bgram = Wvphi^T Wvphi -> frag mat 1
//             else  -> Cgram = Wchi^T Wchi   -> frag mat 2
__global__ __launch_bounds__(256) void k_w1(const float* __restrict__ Wchi,
                                            const float* __restrict__ Wphi,
                                            const float* __restrict__ Wvphi,
                                            float* __restrict__ wcomb,
                                            u16* __restrict__ gf) {
    int b = blockIdx.x, t = threadIdx.x;
    if (b < 64) {
        int idx = b*256 + t;
        int i = idx >> 7, k = idx & 127;
        float acc = 0.f;
        #pragma unroll 8
        for (int m = 0; m < DD; ++m)
            acc = fmaf(Wphi[i*DD+m], Wchi[m*DD+k], acc);
        wcomb[i*DD+k] = acc;
    } else {
        const float* W = (b < 128) ? Wvphi : Wchi;
        int mat = (b < 128) ? 1 : 2;
        int idx = ((b & 63))*256 + t;
        int a = idx >> 7, c = idx & 127;
        float acc = 0.f;
        #pragma unroll 8
        for (int m = 0; m < DD; ++m)
            acc = fmaf(W[m*DD+a], W[m*DD+c], acc);
        gstore(gf, mat, a, c, acc);
    }
}

// grid NB_SCAN + 64: first NB_SCAN blocks do the per-block degree sums;
// blocks >= NB_SCAN compute Agram = Wcomb^T Wcomb -> frag mat 0
__global__ __launch_bounds__(256) void k_scan_bsum(const u32* __restrict__ cnt,
                                                   u32* __restrict__ bsum,
                                                   const float* __restrict__ wcomb,
                                                   u16* __restrict__ gf) {
    if (blockIdx.x >= NB_SCAN) {
        int idx = (blockIdx.x - NB_SCAN)*256 + threadIdx.x;
        int a = idx >> 7, c = idx & 127;
        float acc = 0.f;
        #pragma unroll 8
        for (int m = 0; m < DD; ++m)
            acc = fmaf(wcomb[m*DD+a], wcomb[m*DD+c], acc);
        gstore(gf, 0, a, c, acc);
        return;
    }
    __shared__ u32 s[256];
    int i = blockIdx.x*256 + threadIdx.x;
    s[threadIdx.x] = (i < NNODES) ? cnt[i] : 0u;
    __syncthreads();
    for (int off = 128; off > 0; off >>= 1) {
        if (threadIdx.x < off) s[threadIdx.x] += s[threadIdx.x + off];
        __syncthreads();
    }
    if (threadIdx.x == 0) bsum[blockIdx.x] = s[0];
}

__global__ __launch_bounds__(256) void k_scan_boff(const u32* __restrict__ bsum,
                                                   u32* __restrict__ boff) {
    __shared__ u32 s[256];
    int t = threadIdx.x;
    u32 v = (t < NB_SCAN) ? bsum[t] : 0u;
    s[t] = v;
    __syncthreads();
    for (int off = 1; off < 256; off <<= 1) {
        u32 a = (t >= off) ? s[t - off] : 0u;
        __syncthreads();
        s[t] += a;
        __syncthreads();
    }
    if (t < NB_SCAN) boff[t] = s[t] - v;           // exclusive
}

__global__ __launch_bounds__(256) void k_scan_final(const u32* __restrict__ cnt,
                                                    const u32* __restrict__ boff,
                                                    u32* __restrict__ start,
                                                    u32* __restrict__ cursor) {
    __shared__ u32 s[256];
    int t = threadIdx.x;
    int i = blockIdx.x*256 + t;
    u32 v = (i < NNODES) ? cnt[i] : 0u;
    s[t] = v;
    __syncthreads();
    for (int off = 1; off < 256; off <<= 1) {
        u32 a = (t >= off) ? s[t - off] : 0u;
        __syncthreads();
        s[t] += a;
        __syncthreads();
    }
    if (i < NNODES) {
        u32 val = boff[blockIdx.x] + (s[t] - v);
        start[i]  = val;
        cursor[i] = val;
        if (i == NNODES-1) start[NNODES] = val + v;
    }
}

#define SB (NEDGES/256)       // 6250 scatter blocks
#define GB 782                // gemm blocks: 64 nodes each (last partial)
// grid = SB + GB = 7032; b%9==0 -> gemm (782 exactly), else scatter

template<bool RANK>
__global__ __launch_bounds__(256) void k_mid(const int* __restrict__ ei,
                                             const float* __restrict__ ew,
                                             const u32* __restrict__ start,
                                             u32* __restrict__ cursor,
                                             const u32* __restrict__ rank,
                                             uint2* __restrict__ erec,
                                             const u16* __restrict__ xb,
                                             float* __restrict__ ws,
                                             u16* __restrict__ ab) {
    int b = blockIdx.x, t = threadIdx.x;
    if (b % 9 != 0) {                              // scatter into CSR (packed 8B record)
        int eb = b - b/9 - 1;
        int e = eb*256 + t;
        int r = __builtin_nontemporal_load(&ei[e]);
        u32 pos;
        if (RANK) pos = start[r] + __builtin_nontemporal_load(&rank[e]);
        else      pos = atomicAdd(&cursor[r], 1u);
        u32 c  = (u32)__builtin_nontemporal_load(&ei[NEDGES + e]);
        u32 wb = __float_as_uint(__builtin_nontemporal_load(&ew[e]));
        u64 recv = (u64)c | ((u64)wb << 32);
        __builtin_nontemporal_store(recv, (u64*)&erec[pos]);
        return;
    }
    // gemm role: 4 independent waves, 16 nodes each, MFMA over the 3 Gram matrices
    __shared__ u16 xs[4][16][DD];
    int w = t >> 6, l = t & 63;
    int l15 = l & 15, lq = l >> 4;
    int nb = (b/9)*64 + w*16;
    if (nb >= NNODES) return;

    // A-fragments: lane holds x[nb+l15][kk*32 + lq*8 + j], j=0..7
    const v8s* xbv = (const v8s*)(xb + (size_t)(nb + l15)*DD);
    v8s af[4];
    #pragma unroll
    for (int kk = 0; kk < 4; ++kk) {
        af[kk] = xbv[kk*4 + lq];
        *(v8s*)&xs[w][l15][kk*32 + lq*8] = af[kk];
    }
    const v8s* gf = (const v8s*)ws;                // OFF_GFRAG = 0
    float* phichi = ws + OFF_PHICHI/4;
    float* vsq    = ws + OFF_VSQ/4;

    #pragma unroll
    for (int mat = 0; mat < 3; ++mat) {
        v4f acc[8];
        #pragma unroll
        for (int nt = 0; nt < 8; ++nt) acc[nt] = (v4f){0.f,0.f,0.f,0.f};
        #pragma unroll
        for (int kk = 0; kk < 4; ++kk)
            #pragma unroll
            for (int nt = 0; nt < 8; ++nt)
                acc[nt] = __builtin_amdgcn_mfma_f32_16x16x32_bf16(
                    af[kk], gf[((mat*8 + nt)*4 + kk)*64 + l], acc[nt], 0, 0, 0);
        // D[m][n]: m = lq*4 + r (node), n = nt*16 + l15 (dim)   [m89-verified C/D map]
        if (mat < 2) {                             // store a (mat0) / b (mat1) bf16
            int base = mat ? 128 : 0;
            #pragma unroll
            for (int nt = 0; nt < 8; ++nt)
                #pragma unroll
                for (int r = 0; r < 4; ++r)
                    ab[(size_t)(nb + lq*4 + r)*256 + base + nt*16 + l15] = f2b(acc[nt][r]);
        }
        if (mat >= 1) {                            // x . (G x): vsq (mat1), phichi (mat2)
            float p0 = 0.f, p1 = 0.f, p2 = 0.f, p3 = 0.f;
            #pragma unroll
            for (int nt = 0; nt < 8; ++nt) {
                int nn = nt*16 + l15;
                p0 = fmaf(b2f16(xs[w][lq*4+0][nn]), acc[nt][0], p0);
                p1 = fmaf(b2f16(xs[w][lq*4+1][nn]), acc[nt][1], p1);
                p2 = fmaf(b2f16(xs[w][lq*4+2][nn]), acc[nt][2], p2);
                p3 = fmaf(b2f16(xs[w][lq*4+3][nn]), acc[nt][3], p3);
            }
            #pragma unroll
            for (int mask = 1; mask < 16; mask <<= 1) {
                p0 += __shfl_xor(p0, mask);
                p1 += __shfl_xor(p1, mask);
                p2 += __shfl_xor(p2, mask);
                p3 += __shfl_xor(p3, mask);
            }
            if (l15 == 0) {
                int n0 = nb + lq*4;
                if (mat == 1) {
                    vsq[n0+0] = p0; vsq[n0+1] = p1; vsq[n0+2] = p2; vsq[n0+3] = p3;
                } else {
                    phichi[n0+0] = tanh_pos(sqrtf(fmaxf(p0, 0.f)));
                    phichi[n0+1] = tanh_pos(sqrtf(fmaxf(p1, 0.f)));
                    phichi[n0+2] = tanh_pos(sqrtf(fmaxf(p2, 0.f)));
                    phichi[n0+3] = tanh_pos(sqrtf(fmaxf(p3, 0.f)));
                }
            }
        }
    }
}

// one wave per node; 16 edges per MFMA tile.
// A rows: 0 = a_r, 1 = b_r (bf16 from ab), rows 2-15 zero.
// B cols: 16 gathered x_c. D row=lq*4+reg, col=l15 (R2/R3-validated maps).
// R6: erec prefetch pipeline + shfl pre-reduce (LDS 33792 -> 16896 for occupancy).
__global__ __launch_bounds__(256) void k_accum(const float* __restrict__ x,
                                               const float* __restrict__ phichi,
                                               const float* __restrict__ vsq,
                                               const u32* __restrict__ start,
                                               const uint2* __restrict__ erec,
                                               const u16* __restrict__ xb,
                                               const u16* __restrict__ ab,
                                               float* __restrict__ out) {
    __shared__ float red[4][8][132];               // per-wave transpose-reduce (+4 pad)
    int w = threadIdx.x >> 6, lane = threadIdx.x & 63;
    int node = blockIdx.x*4 + w;
    int l15 = lane & 15, lq = lane >> 4;

    u32 s0 = start[node];
    u32 n  = start[node+1] - s0;
    float vq_r = vsq[node];

    // A fragments: row l15==0 -> a_r slice, row l15==1 -> b_r slice, else 0
    v8s zero = {0,0,0,0,0,0,0,0};
    v8s afr[4];
    {
        const v8s* abv = (const v8s*)(ab + (size_t)node*256 + ((l15 == 1) ? 128 : 0));
        bool keep = (l15 < 2);
        #pragma unroll
        for (int kk = 0; kk < 4; ++kk) {
            v8s v = abv[kk*4 + lq];
            afr[kk] = keep ? v : zero;
        }
    }

    float accl[4][8];                              // per-lane accv partial, frag layout
    #pragma unroll
    for (int kk = 0; kk < 4; ++kk)
        #pragma unroll
        for (int j = 0; j < 8; ++j) accl[kk][j] = 0.f;
    float sphi = 0.f, wsum = 0.f;

    u32 ntiles = (n + 15) >> 4;

    auto ldr = [&](u32 tt) -> u64 {                // edge record, clamped index
        u32 off = tt*16 + (u32)l15;
        u32 eidx = (off < n) ? (s0 + off) : s0;
        return __builtin_nontemporal_load((const u64*)&erec[eidx]);
    };

    if (ntiles) {
        u64 rc = ldr(0);                           // current tile's record
        for (u32 tt = 0; tt < ntiles; ++tt) {
            u64 rn = (tt + 1 < ntiles) ? ldr(tt + 1) : rc;   // prefetch next
            u32 c = (u32)rc;
            bool valid = (tt*16 + (u32)l15) < n;
            float w_e = valid ? __uint_as_float((u32)(rc >> 32)) : 0.f;
            float vqc = vsq[c];
            const v8s* xcv = (const v8s*)(xb + (size_t)c*128);
            v8s bfr[4];
            #pragma unroll
            for (int kk = 0; kk < 4; ++kk) bfr[kk] = xcv[kk*4 + lq];

            v4f d = {0.f, 0.f, 0.f, 0.f};
            #pragma unroll
            for (int kk = 0; kk < 4; ++kk)
                d = __builtin_amdgcn_mfma_f32_16x16x32_bf16(afr[kk], bfr[kk], d, 0, 0, 0);
            // lq==0 lanes: d[0]=adot(edge l15), d[1]=bdot; others exact 0 (zero A rows)
            float ss = fmaxf(vq_r + vqc - 2.f*d[1], 0.f);
            float psi = w_e * tanh_pos(fabsf(d[0])) * tanh_pos(__fdividef(1.f, sqrtf(ss) + EPSF));
            float psi_b = __shfl(psi, l15);        // broadcast edge l15's psi to all lq
            sphi += psi_b;
            wsum += w_e;
            #pragma unroll
            for (int kk = 0; kk < 4; ++kk) {
                u32* pw = (u32*)&bfr[kk];
                #pragma unroll
                for (int q = 0; q < 4; ++q) {
                    accl[kk][2*q]   = fmaf(psi_b, b2f_lo(pw[q]), accl[kk][2*q]);
                    accl[kk][2*q+1] = fmaf(psi_b, b2f_hi(pw[q]), accl[kk][2*q+1]);
                }
            }
            rc = rn;
        }
    }

    // reduce sphi/wsum over the 16 edge-slots (lq copies identical afterwards)
    #pragma unroll
    for (int mask = 1; mask < 16; mask <<= 1) {
        sphi += __shfl_xor(sphi, mask);
        wsum += __shfl_xor(wsum, mask);
    }

    // pre-reduce accl over adjacent edge-slot pairs (halves red rows -> LDS 16.9KB)
    #pragma unroll
    for (int kk = 0; kk < 4; ++kk)
        #pragma unroll
        for (int j = 0; j < 8; ++j)
            accl[kk][j] += __shfl_xor(accl[kk][j], 1);

    if ((l15 & 1) == 0) {
        int e8 = l15 >> 1;
        #pragma unroll
        for (int kk = 0; kk < 4; ++kk) {
            *(float4*)&red[w][e8][kk*32 + lq*8]     = *(float4*)&accl[kk][0];
            *(float4*)&red[w][e8][kk*32 + lq*8 + 4] = *(float4*)&accl[kk][4];
        }
    }
    __syncthreads();
    float a0 = 0.f, a1 = 0.f;
    #pragma unroll
    for (int e = 0; e < 8; ++e) {
        float2 v = *(const float2*)&red[w][e][lane*2];
        a0 += v.x; a1 += v.y;
    }

    float ia = (n == 0) ? 0.f : __fdividef(1.f, wsum * phichi[node]);
    float scale = 1.f - ia * sphi;
    float2 xv = *(const float2*)(x + (size_t)node*DD + lane*2);
    v2f o;
    o.x = xv.x*scale + ia*a0;
    o.y = xv.y*scale + ia*a1;
    __builtin_nontemporal_store(o, (v2f*)(out + (size_t)node*DD + lane*2));
}

extern "C" void kernel_launch(void* const* d_in, const int* in_sizes, int n_in,
                              void* d_out, int out_size, void* d_ws, size_t ws_size,
                              hipStream_t stream) {
    const float* x     = (const float*)d_in[0];
    const int*   ei    = (const int*)d_in[1];
    const float* ew    = (const float*)d_in[2];
    const float* Wchi  = (const float*)d_in[3];
    const float* Wphi  = (const float*)d_in[4];
    const float* Wvphi = (const float*)d_in[5];
    float* out = (float*)d_out;
    float* ws  = (float*)d_ws;
    char*  wsb = (char*)d_ws;

    float* phichi = (float*)(wsb + OFF_PHICHI);
    float* vsq    = (float*)(wsb + OFF_VSQ);
    u32*   cnt    = (u32*)  (wsb + OFF_CNT);
    u32*   cursor = (u32*)  (wsb + OFF_CNT);    // alias: cnt dead after scans
    u32*   start  = (u32*)  (wsb + OFF_START);
    u32*   bsum   = (u32*)  (wsb + OFF_BSUM);
    u32*   boff   = (u32*)  (wsb + OFF_BOFF);
    u16*   gf     = (u16*)  (wsb + OFF_GFRAG);
    u16*   ab     = (u16*)  (wsb + OFF_AB);
    u16*   xb     = (u16*)  (wsb + OFF_XB);
    uint2* erec   = (uint2*)(wsb + OFF_EREC);
    float* wcomb  = (float*)(wsb + OFF_WCOMB);  // temp, overlays erec
    u32*   rank   = (u32*)  (wsb + OFF_RANK);

    bool use_rank = (ws_size >= (size_t)WS_NEED_RANK);

    hipMemsetAsync(wsb + OFF_CNT, 0, 200000, stream);
    if (use_rank) {
        k_prep<true><<<dim3(HB+IB), dim3(256), 0, stream>>>(ei, x, cnt, xb, rank);
    } else {
        k_prep<false><<<dim3(HB+IB), dim3(256), 0, stream>>>(ei, x, cnt, xb, rank);
    }
    k_w1<<<dim3(192), dim3(256), 0, stream>>>(Wchi, Wphi, Wvphi, wcomb, gf);
    k_scan_bsum<<<dim3(NB_SCAN+64), dim3(256), 0, stream>>>(cnt, bsum, wcomb, gf);
    k_scan_boff<<<dim3(1), dim3(256), 0, stream>>>(bsum, boff);
    k_scan_final<<<dim3(NB_SCAN), dim3(256), 0, stream>>>(cnt, boff, start, cursor);
    if (use_rank) {
        k_mid<true><<<dim3(SB+GB), dim3(256), 0, stream>>>(ei, ew, start, cursor, rank, erec, xb, ws, ab);
    } else {
        k_mid<false><<<dim3(SB+GB), dim3(256), 0, stream>>>(ei, ew, start, cursor, rank, erec, xb, ws, ab);
    }
    k_accum<<<dim3(NNODES/4), dim3(256), 0, stream>>>(x, phichi, vsq, start, erec, xb, ab, out);
}

// Round 7
// 231.529 us; speedup vs baseline: 2.0314x; 1.1308x over previous
//
#include <hip/hip_runtime.h>
#include <hip/hip_bf16.h>

#define NNODES 50000
#define NEDGES 1600000
#define DD 128
#define EPSF 1e-6f
#define NB_SCAN 196   // ceil(50000/256)

using u32 = unsigned int;
using u16 = unsigned short;
using u64 = unsigned long long;
typedef __attribute__((ext_vector_type(8))) short v8s;   // 8 x bf16 (4 VGPR)
typedef __attribute__((ext_vector_type(4))) float v4f;   // mfma accumulator
typedef __attribute__((ext_vector_type(4))) int   v4i;   // i8 mfma operand (16 i8)
typedef __attribute__((ext_vector_type(2))) float v2f;   // nontemporal-storable pair

static __device__ __forceinline__ float b2f16(u16 v) { return __uint_as_float(((u32)v) << 16); }
static __device__ __forceinline__ u16 f2b(float f) {
    u32 u = __float_as_uint(f);
    return (u16)((u + 0x7fffu + ((u >> 16) & 1u)) >> 16);
}
static __device__ __forceinline__ float tanh_pos(float a) {   // a >= 0, fast
    float e = __expf(-2.f * a);
    return __fdividef(1.f - e, 1.f + e);
}

// workspace byte offsets
#define OFF_GFRAG  0          // 3 * 32KB bf16 Gram matrices in MFMA B-frag layout
#define OFF_PHICHI 98304      // 50000 f32
#define OFF_VSX    298304     // 50000 float2 : (vsq, xscale) per node
#define OFF_CNT    698304     // 50000 u32 (aliased as cursor in fallback path)
#define OFF_START  898304     // 50001 u32 (pad to 1098320)
#define OFF_BSUM   1098320    // 196 u32 (800 B)
#define OFF_BOFF   1099120    // 196 u32 (800 B)
#define OFF_ABSC   1099920    // 50000 float2 : (ascale, bscale)
#define OFF_AQ     1499920    // 50000*128 i8 : a vector, per-node scaled
#define OFF_BQ     7899920    // 50000*128 i8 : b vector
#define OFF_XB     14299920   // 50000*128 bf16 : x (k_mid GEMM A operand)
#define OFF_XQ     27099920   // 50000*128 i8 : x, per-node scaled (gather pool)
#define OFF_EREC   33499920   // 1.6M u32 : (col<<15)|bf16w
#define OFF_WCOMB  33499920   // 128*128 f32 TEMP, overlays EREC (dead before k_mid)
#define OFF_RANK   39899920   // 1.6M u16 -> ends 43,099,920
#define WS_NEED_RANK 43099920ull

// store val=G[a][c] into MFMA B-fragment layout for mfma_f32_16x16x32_bf16
static __device__ __forceinline__ void gstore(u16* gf, int mat, int a, int c, float v) {
    int lane = (((a >> 3) & 3) << 4) | (c & 15);
    int u = ((((mat*8 + (c >> 4))*4 + (a >> 5))*64 + lane) << 3) | (a & 7);
    gf[u] = f2b(v);
}

#define HB (NEDGES/256)       // 6250 hist blocks
#define XBLK (NNODES/4)       // 12500 x-quant blocks (1 node/wave)

template<bool RANK>
__global__ __launch_bounds__(256) void k_prep(const int* __restrict__ ei,
                                              const float* __restrict__ x,
                                              u32* __restrict__ cnt,
                                              u16* __restrict__ xb,
                                              char* __restrict__ xq,
                                              float* __restrict__ vsx,
                                              u16* __restrict__ rank) {
    int b = blockIdx.x, t = threadIdx.x;
    if (b < HB) {                                  // histogram (+ per-edge rank)
        int e = b*256 + t;
        if (RANK) rank[e] = (u16)atomicAdd(&cnt[ei[e]], 1u);
        else      atomicAdd(&cnt[ei[e]], 1u);
        return;
    }
    // x -> bf16 xb + i8 xq (per-node absmax scale). 1 node per wave.
    int w = t >> 6, lane = t & 63;
    int node = (b - HB)*4 + w;
    float2 xv = ((const float2*)(x + (size_t)node*DD))[lane];
    u32 pk = (u32)f2b(xv.x) | ((u32)f2b(xv.y) << 16);
    ((u32*)xb)[node*64 + lane] = pk;
    float m = fmaxf(fabsf(xv.x), fabsf(xv.y));
    #pragma unroll
    for (int mask = 1; mask < 64; mask <<= 1)
        m = fmaxf(m, __shfl_xor(m, mask));
    float inv = (m > 0.f) ? 127.f/m : 0.f;
    int q0 = (int)rintf(xv.x*inv), q1 = (int)rintf(xv.y*inv);
    ((u16*)xq)[node*64 + lane] = (u16)((q0 & 0xff) | ((q1 & 0xff) << 8));
    if (lane == 0) vsx[2*node + 1] = m * (1.f/127.f);
}

// 192 blocks: b<64 -> Wcomb = Wphi@Wchi (fp32 temp);
//             b<128 -> Bgram -> frag mat 1;  else Cgram -> frag mat 2
__global__ __launch_bounds__(256) void k_w1(const float* __restrict__ Wchi,
                                            const float* __restrict__ Wphi,
                                            const float* __restrict__ Wvphi,
                                            float* __restrict__ wcomb,
                                            u16* __restrict__ gf) {
    int b = blockIdx.x, t = threadIdx.x;
    if (b < 64) {
        int idx = b*256 + t;
        int i = idx >> 7, k = idx & 127;
        float acc = 0.f;
        #pragma unroll 8
        for (int m = 0; m < DD; ++m)
            acc = fmaf(Wphi[i*DD+m], Wchi[m*DD+k], acc);
        wcomb[i*DD+k] = acc;
    } else {
        const float* W = (b < 128) ? Wvphi : Wchi;
        int mat = (b < 128) ? 1 : 2;
        int idx = ((b & 63))*256 + t;
        int a = idx >> 7, c = idx & 127;
        float acc = 0.f;
        #pragma unroll 8
        for (int m = 0; m < DD; ++m)
            acc = fmaf(W[m*DD+a], W[m*DD+c], acc);
        gstore(gf, mat, a, c, acc);
    }
}

// grid NB_SCAN + 64: degree block-sums; extra blocks do Agram -> frag mat 0
__global__ __launch_bounds__(256) void k_scan_bsum(const u32* __restrict__ cnt,
                                                   u32* __restrict__ bsum,
                                                   const float* __restrict__ wcomb,
                                                   u16* __restrict__ gf) {
    if (blockIdx.x >= NB_SCAN) {
        int idx = (blockIdx.x - NB_SCAN)*256 + threadIdx.x;
        int a = idx >> 7, c = idx & 127;
        float acc = 0.f;
        #pragma unroll 8
        for (int m = 0; m < DD; ++m)
            acc = fmaf(wcomb[m*DD+a], wcomb[m*DD+c], acc);
        gstore(gf, 0, a, c, acc);
        return;
    }
    __shared__ u32 s[256];
    int i = blockIdx.x*256 + threadIdx.x;
    s[threadIdx.x] = (i < NNODES) ? cnt[i] : 0u;
    __syncthreads();
    for (int off = 128; off > 0; off >>= 1) {
        if (threadIdx.x < off) s[threadIdx.x] += s[threadIdx.x + off];
        __syncthreads();
    }
    if (threadIdx.x == 0) bsum[blockIdx.x] = s[0];
}

__global__ __launch_bounds__(256) void k_scan_boff(const u32* __restrict__ bsum,
                                                   u32* __restrict__ boff) {
    __shared__ u32 s[256];
    int t = threadIdx.x;
    u32 v = (t < NB_SCAN) ? bsum[t] : 0u;
    s[t] = v;
    __syncthreads();
    for (int off = 1; off < 256; off <<= 1) {
        u32 a = (t >= off) ? s[t - off] : 0u;
        __syncthreads();
        s[t] += a;
        __syncthreads();
    }
    if (t < NB_SCAN) boff[t] = s[t] - v;           // exclusive
}

__global__ __launch_bounds__(256) void k_scan_final(const u32* __restrict__ cnt,
                                                    const u32* __restrict__ boff,
                                                    u32* __restrict__ start,
                                                    u32* __restrict__ cursor) {
    __shared__ u32 s[256];
    int t = threadIdx.x;
    int i = blockIdx.x*256 + t;
    u32 v = (i < NNODES) ? cnt[i] : 0u;
    s[t] = v;
    __syncthreads();
    for (int off = 1; off < 256; off <<= 1) {
        u32 a = (t >= off) ? s[t - off] : 0u;
        __syncthreads();
        s[t] += a;
        __syncthreads();
    }
    if (i < NNODES) {
        u32 val = boff[blockIdx.x] + (s[t] - v);
        start[i]  = val;
        cursor[i] = val;
        if (i == NNODES-1) start[NNODES] = val + v;
    }
}

#define SB (NEDGES/256)       // 6250 scatter blocks
#define GB 782                // gemm blocks: 64 nodes each
// grid = SB + GB = 7032; b%9==0 -> gemm (782 exactly), else scatter

template<bool RANK>
__global__ __launch_bounds__(256) void k_mid(const int* __restrict__ ei,
                                             const float* __restrict__ ew,
                                             const u32* __restrict__ start,
                                             u32* __restrict__ cursor,
                                             const u16* __restrict__ rank,
                                             u32* __restrict__ erec,
                                             const u16* __restrict__ xb,
                                             float* __restrict__ ws,
                                             char* __restrict__ aq,
                                             char* __restrict__ bq,
                                             float* __restrict__ absc) {
    int b = blockIdx.x, t = threadIdx.x;
    if (b % 9 != 0) {                              // scatter into CSR (4B packed record)
        int eb = b - b/9 - 1;
        int e = eb*256 + t;
        int r = __builtin_nontemporal_load(&ei[e]);
        u32 pos;
        if (RANK) pos = start[r] + (u32)__builtin_nontemporal_load(&rank[e]);
        else      pos = atomicAdd(&cursor[r], 1u);
        u32 c  = (u32)__builtin_nontemporal_load(&ei[NEDGES + e]);
        u32 wb = (u32)f2b(__builtin_nontemporal_load(&ew[e])) & 0x7fffu;
        erec[pos] = (c << 15) | wb;                // plain store: let L2 merge lines
        return;
    }
    // gemm role: 4 waves, 16 nodes each, MFMA over the 3 Gram matrices
    __shared__ u16 xs[4][16][DD];
    int w = t >> 6, l = t & 63;
    int l15 = l & 15, lq = l >> 4;
    int nb = (b/9)*64 + w*16;
    if (nb >= NNODES) return;

    const v8s* xbv = (const v8s*)(xb + (size_t)(nb + l15)*DD);
    v8s af[4];
    #pragma unroll
    for (int kk = 0; kk < 4; ++kk) {
        af[kk] = xbv[kk*4 + lq];
        *(v8s*)&xs[w][l15][kk*32 + lq*8] = af[kk];
    }
    const v8s* gf = (const v8s*)ws;                // OFF_GFRAG = 0
    float* phichi = ws + OFF_PHICHI/4;
    float* vsx    = ws + OFF_VSX/4;
    float sa4[4] = {0.f, 0.f, 0.f, 0.f};

    #pragma unroll
    for (int mat = 0; mat < 3; ++mat) {
        v4f acc[8];
        #pragma unroll
        for (int nt = 0; nt < 8; ++nt) acc[nt] = (v4f){0.f,0.f,0.f,0.f};
        #pragma unroll
        for (int kk = 0; kk < 4; ++kk)
            #pragma unroll
            for (int nt = 0; nt < 8; ++nt)
                acc[nt] = __builtin_amdgcn_mfma_f32_16x16x32_bf16(
                    af[kk], gf[((mat*8 + nt)*4 + kk)*64 + l], acc[nt], 0, 0, 0);
        // D[m][n]: m = lq*4 + r (node), n = nt*16 + l15 (dim)
        if (mat < 2) {                             // quantize a/b to i8, per-node scale
            float mx[4] = {0.f, 0.f, 0.f, 0.f};
            #pragma unroll
            for (int nt = 0; nt < 8; ++nt)
                #pragma unroll
                for (int r = 0; r < 4; ++r)
                    mx[r] = fmaxf(mx[r], fabsf(acc[nt][r]));
            #pragma unroll
            for (int mask = 1; mask < 16; mask <<= 1)
                #pragma unroll
                for (int r = 0; r < 4; ++r)
                    mx[r] = fmaxf(mx[r], __shfl_xor(mx[r], mask));
            float iv[4], sc[4];
            #pragma unroll
            for (int r = 0; r < 4; ++r) {
                iv[r] = (mx[r] > 0.f) ? 127.f/mx[r] : 0.f;
                sc[r] = mx[r] * (1.f/127.f);
            }
            char* qdst = mat ? bq : aq;
            #pragma unroll
            for (int nt = 0; nt < 8; ++nt)
                #pragma unroll
                for (int r = 0; r < 4; ++r)
                    qdst[(size_t)(nb + lq*4 + r)*128 + nt*16 + l15] =
                        (char)(int)rintf(acc[nt][r]*iv[r]);
            if (mat == 0) {
                #pragma unroll
                for (int r = 0; r < 4; ++r) sa4[r] = sc[r];
            } else if (l15 == 0) {
                #pragma unroll
                for (int r = 0; r < 4; ++r)
                    *(v2f*)&absc[2*(nb + lq*4 + r)] = (v2f){sa4[r], sc[r]};
            }
        }
        if (mat >= 1) {                            // x . (G x): vsq (mat1), phichi (mat2)
            float p0 = 0.f, p1 = 0.f, p2 = 0.f, p3 = 0.f;
            #pragma unroll
            for (int nt = 0; nt < 8; ++nt) {
                int nn = nt*16 + l15;
                p0 = fmaf(b2f16(xs[w][lq*4+0][nn]), acc[nt][0], p0);
                p1 = fmaf(b2f16(xs[w][lq*4+1][nn]), acc[nt][1], p1);
                p2 = fmaf(b2f16(xs[w][lq*4+2][nn]), acc[nt][2], p2);
                p3 = fmaf(b2f16(xs[w][lq*4+3][nn]), acc[nt][3], p3);
            }
            #pragma unroll
            for (int mask = 1; mask < 16; mask <<= 1) {
                p0 += __shfl_xor(p0, mask);
                p1 += __shfl_xor(p1, mask);
                p2 += __shfl_xor(p2, mask);
                p3 += __shfl_xor(p3, mask);
            }
            if (l15 == 0) {
                int n0 = nb + lq*4;
                if (mat == 1) {
                    vsx[2*(n0+0)] = p0; vsx[2*(n0+1)] = p1;
                    vsx[2*(n0+2)] = p2; vsx[2*(n0+3)] = p3;
                } else {
                    phichi[n0+0] = tanh_pos(sqrtf(fmaxf(p0, 0.f)));
                    phichi[n0+1] = tanh_pos(sqrtf(fmaxf(p1, 0.f)));
                    phichi[n0+2] = tanh_pos(sqrtf(fmaxf(p2, 0.f)));
                    phichi[n0+3] = tanh_pos(sqrtf(fmaxf(p3, 0.f)));
                }
            }
        }
    }
}

// one wave per node; 16 edges per i8-MFMA tile (K=128 via 2 chained MFMAs).
// A rows: 0 = a_r, 1 = b_r (i8), rows 2-15 zero. B cols: 16 gathered i8 x_c.
// Scales: sa,sb per row node (absc), sx per col node (vsx.y). Dots exact in i32.
__global__ __launch_bounds__(256) void k_accum(const float* __restrict__ x,
                                               const float* __restrict__ phichi,
                                               const float* __restrict__ vsx,
                                               const float* __restrict__ absc,
                                               const u32* __restrict__ start,
                                               const u32* __restrict__ erec,
                                               const char* __restrict__ xq,
                                               const char* __restrict__ aq,
                                               const char* __restrict__ bq,
                                               float* __restrict__ out) {
    __shared__ float red[4][8][132];
    int w = threadIdx.x >> 6, lane = threadIdx.x & 63;
    int node = blockIdx.x*4 + w;
    int l15 = lane & 15, lq = lane >> 4;

    u32 s0 = start[node];
    u32 n  = start[node+1] - s0;
    float vq_r = vsx[2*node];
    float2 sab = *(const float2*)&absc[2*node];

    v4i zero4 = {0, 0, 0, 0};
    v4i afr[2];
    {
        const char* src = (l15 == 1) ? bq : aq;
        const v4i* p = (const v4i*)(src + (size_t)node*128);
        bool keep = (l15 < 2);
        #pragma unroll
        for (int kk = 0; kk < 2; ++kk) {
            v4i v = p[kk*4 + lq];
            afr[kk] = keep ? v : zero4;
        }
    }

    float accl[2][16];
    #pragma unroll
    for (int kk = 0; kk < 2; ++kk)
        #pragma unroll
        for (int j = 0; j < 16; ++j) accl[kk][j] = 0.f;
    float sphi = 0.f, wsum = 0.f;

    u32 ntiles = (n + 15) >> 4;

    auto ldr = [&](u32 tt) -> u32 {
        u32 off = tt*16 + (u32)l15;
        u32 eidx = (off < n) ? (s0 + off) : s0;
        return __builtin_nontemporal_load(&erec[eidx]);
    };

    if (ntiles) {
        u32 rc = ldr(0);
        for (u32 tt = 0; tt < ntiles; ++tt) {
            u32 rn = (tt + 1 < ntiles) ? ldr(tt + 1) : rc;
            u32 c = rc >> 15;
            bool valid = (tt*16 + (u32)l15) < n;
            float w_e = valid ? __uint_as_float((rc & 0x7fffu) << 16) : 0.f;
            float2 vx = *(const float2*)&vsx[2*c];   // (vsq_c, sx_c)
            const v4i* xcv = (const v4i*)(xq + (size_t)c*128);
            v4i bfr[2];
            bfr[0] = xcv[lq];
            bfr[1] = xcv[4 + lq];

            v4i d = zero4;
            d = __builtin_amdgcn_mfma_i32_16x16x64_i8(afr[0], bfr[0], d, 0, 0, 0);
            d = __builtin_amdgcn_mfma_i32_16x16x64_i8(afr[1], bfr[1], d, 0, 0, 0);
            // lq==0 lanes: d[0]=adot_int(edge l15), d[1]=bdot_int; others exact 0
            float adot = (float)d[0] * (sab.x * vx.y);
            float bdot = (float)d[1] * (sab.y * vx.y);
            float ss = fmaxf(vq_r + vx.x - 2.f*bdot, 0.f);
            float psi = w_e * tanh_pos(fabsf(adot)) * tanh_pos(__fdividef(1.f, sqrtf(ss) + EPSF));
            float psi_b = __shfl(psi, l15);          // edge l15's psi to all lq groups
            sphi += psi_b;
            wsum += w_e;
            float psx = psi_b * vx.y;                // fold sx_c into the accumulate
            #pragma unroll
            for (int kk = 0; kk < 2; ++kk) {
                const int* pw = (const int*)&bfr[kk];
                #pragma unroll
                for (int wd = 0; wd < 4; ++wd) {
                    int word = pw[wd];
                    accl[kk][wd*4+0] = fmaf(psx, (float)((word << 24) >> 24), accl[kk][wd*4+0]);
                    accl[kk][wd*4+1] = fmaf(psx, (float)((word << 16) >> 24), accl[kk][wd*4+1]);
                    accl[kk][wd*4+2] = fmaf(psx, (float)((word <<  8) >> 24), accl[kk][wd*4+2]);
                    accl[kk][wd*4+3] = fmaf(psx, (float)( word        >> 24), accl[kk][wd*4+3]);
                }
            }
            rc = rn;
        }
    }

    // reduce sphi/wsum over the 16 edge-slots
    #pragma unroll
    for (int mask = 1; mask < 16; mask <<= 1) {
        sphi += __shfl_xor(sphi, mask);
        wsum += __shfl_xor(wsum, mask);
    }

    // pre-reduce accl over adjacent edge-slot pairs, then LDS transpose-reduce
    #pragma unroll
    for (int kk = 0; kk < 2; ++kk)
        #pragma unroll
        for (int j = 0; j < 16; ++j)
            accl[kk][j] += __shfl_xor(accl[kk][j], 1);

    if ((l15 & 1) == 0) {
        int e8 = l15 >> 1;
        #pragma unroll
        for (int kk = 0; kk < 2; ++kk) {
            int base = kk*64 + lq*16;                // dim = kk*64 + lq*16 + j
            *(float4*)&red[w][e8][base]      = *(float4*)&accl[kk][0];
            *(float4*)&red[w][e8][base + 4]  = *(float4*)&accl[kk][4];
            *(float4*)&red[w][e8][base + 8]  = *(float4*)&accl[kk][8];
            *(float4*)&red[w][e8][base + 12] = *(float4*)&accl[kk][12];
        }
    }
    __syncthreads();
    float a0 = 0.f, a1 = 0.f;
    #pragma unroll
    for (int e = 0; e < 8; ++e) {
        float2 v = *(const float2*)&red[w][e][lane*2];
        a0 += v.x; a1 += v.y;
    }

    float ia = (n == 0) ? 0.f : __fdividef(1.f, wsum * phichi[node]);
    float scale = 1.f - ia * sphi;
    float2 xv = *(const float2*)(x + (size_t)node*DD + lane*2);
    v2f o;
    o.x = xv.x*scale + ia*a0;
    o.y = xv.y*scale + ia*a1;
    __builtin_nontemporal_store(o, (v2f*)(out + (size_t)node*DD + lane*2));
}

extern "C" void kernel_launch(void* const* d_in, const int* in_sizes, int n_in,
                              void* d_out, int out_size, void* d_ws, size_t ws_size,
                              hipStream_t stream) {
    const float* x     = (const float*)d_in[0];
    const int*   ei    = (const int*)d_in[1];
    const float* ew    = (const float*)d_in[2];
    const float* Wchi  = (const float*)d_in[3];
    const float* Wphi  = (const float*)d_in[4];
    const float* Wvphi = (const float*)d_in[5];
    float* out = (float*)d_out;
    float* ws  = (float*)d_ws;
    char*  wsb = (char*)d_ws;

    float* phichi = (float*)(wsb + OFF_PHICHI);
    float* vsx    = (float*)(wsb + OFF_VSX);
    u32*   cnt    = (u32*)  (wsb + OFF_CNT);
    u32*   cursor = (u32*)  (wsb + OFF_CNT);    // alias: cnt dead after scans
    u32*   start  = (u32*)  (wsb + OFF_START);
    u32*   bsum   = (u32*)  (wsb + OFF_BSUM);
    u32*   boff   = (u32*)  (wsb + OFF_BOFF);
    u16*   gf     = (u16*)  (wsb + OFF_GFRAG);
    float* absc   = (float*)(wsb + OFF_ABSC);
    char*  aq     = (char*) (wsb + OFF_AQ);
    char*  bq     = (char*) (wsb + OFF_BQ);
    u16*   xb     = (u16*)  (wsb + OFF_XB);
    char*  xq     = (char*) (wsb + OFF_XQ);
    u32*   erec   = (u32*)  (wsb + OFF_EREC);
    float* wcomb  = (float*)(wsb + OFF_WCOMB);  // temp, overlays erec
    u16*   rank   = (u16*)  (wsb + OFF_RANK);

    bool use_rank = (ws_size >= (size_t)WS_NEED_RANK);

    hipMemsetAsync(wsb + OFF_CNT, 0, 200000, stream);
    if (use_rank) {
        k_prep<true><<<dim3(HB+XBLK), dim3(256), 0, stream>>>(ei, x, cnt, xb, xq, vsx, rank);
    } else {
        k_prep<false><<<dim3(HB+XBLK), dim3(256), 0, stream>>>(ei, x, cnt, xb, xq, vsx, rank);
    }
    k_w1<<<dim3(192), dim3(256), 0, stream>>>(Wchi, Wphi, Wvphi, wcomb, gf);
    k_scan_bsum<<<dim3(NB_SCAN+64), dim3(256), 0, stream>>>(cnt, bsum, wcomb, gf);
    k_scan_boff<<<dim3(1), dim3(256), 0, stream>>>(bsum, boff);
    k_scan_final<<<dim3(NB_SCAN), dim3(256), 0, stream>>>(cnt, boff, start, cursor);
    if (use_rank) {
        k_mid<true><<<dim3(SB+GB), dim3(256), 0, stream>>>(ei, ew, start, cursor, rank, erec, xb, ws, aq, bq, absc);
    } else {
        k_mid<false><<<dim3(SB+GB), dim3(256), 0, stream>>>(ei, ew, start, cursor, rank, erec, xb, ws, aq, bq, absc);
    }
    k_accum<<<dim3(NNODES/4), dim3(256), 0, stream>>>(x, phichi, vsx, absc, start, erec, xq, aq, bq, out);
}

// Round 8
// 226.343 us; speedup vs baseline: 2.0780x; 1.0229x over previous
//
#include <hip/hip_runtime.h>
#include <hip/hip_bf16.h>

#define NNODES 50000
#define NEDGES 1600000
#define DD 128
#define EPSF 1e-6f
#define NB_SCAN 196   // ceil(50000/256)
#define NPART 64      // edge partitions for LDS histogram
#define EPP 25000     // edges per partition (NPART*EPP = NEDGES)
#define RGSZ 12500    // rows per rowgroup (4 rowgroups)

using u32 = unsigned int;
using u16 = unsigned short;
using u64 = unsigned long long;
typedef __attribute__((ext_vector_type(8))) short v8s;   // 8 x bf16 (4 VGPR)
typedef __attribute__((ext_vector_type(4))) float v4f;   // mfma accumulator
typedef __attribute__((ext_vector_type(4))) int   v4i;   // i8 mfma operand (16 i8)
typedef __attribute__((ext_vector_type(2))) float v2f;   // nontemporal-storable pair

static __device__ __forceinline__ float b2f16(u16 v) { return __uint_as_float(((u32)v) << 16); }
static __device__ __forceinline__ u16 f2b(float f) {
    u32 u = __float_as_uint(f);
    return (u16)((u + 0x7fffu + ((u >> 16) & 1u)) >> 16);
}
static __device__ __forceinline__ float tanh_pos(float a) {   // a >= 0, fast
    float e = __expf(-2.f * a);
    return __fdividef(1.f - e, 1.f + e);
}

// workspace byte offsets
#define OFF_GFRAG  0          // 3 * 32KB bf16 Gram matrices in MFMA B-frag layout
#define OFF_PHICHI 98304      // 50000 f32
#define OFF_VSX    298304     // 50000 float2 : (vsq, xscale) per node
#define OFF_CNT    698304     // 50000 u32 row totals (cursor alias in fallback)
#define OFF_START  898304     // 50001 u32 (pad to 1098320)
#define OFF_BSUM   1098320    // 196 u32 (800 B)
#define OFF_BOFF   1099120    // 196 u32 (800 B)
#define OFF_ABSC   1099920    // 50000 float2 : (ascale, bscale)
#define OFF_AQ     1499920    // 50000*128 i8 : a vector, per-node scaled
#define OFF_BQ     7899920    // 50000*128 i8 : b vector
#define OFF_XB     14299920   // 50000*128 bf16 : x (k_mid GEMM A operand)
#define OFF_XQ     27099920   // 50000*128 i8 : x, per-node scaled (gather pool)
#define OFF_EREC   33499920   // 1.6M u32 : (col<<15)|bf16w
#define OFF_WCOMB  33499920   // 128*128 f32 TEMP, overlays EREC (dead before k_mid)
#define OFF_RANK   39899920   // 1.6M u16 : rank within (partition,row)
#define OFF_CBASE  43099920   // 64*50000 u32 : per-(part,row) counts -> exclusive bases
#define WS_NEED_RANK 55899920ull

// store val=G[a][c] into MFMA B-fragment layout for mfma_f32_16x16x32_bf16
static __device__ __forceinline__ void gstore(u16* gf, int mat, int a, int c, float v) {
    int lane = (((a >> 3) & 3) << 4) | (c & 15);
    int u = ((((mat*8 + (c >> 4))*4 + (a >> 5))*64 + lane) << 3) | (a & 7);
    gf[u] = f2b(v);
}

#define HB (NEDGES/256)       // 6250 fallback hist blocks
#define XBLK (NNODES/4)       // 12500 x-quant blocks (1 node/wave)

// LDS histogram: 64 partitions x 4 rowgroups = 256 WGs. Zero device-scope atomics.
__global__ __launch_bounds__(256) void k_hist(const int* __restrict__ ei,
                                              u16* __restrict__ rank,
                                              u32* __restrict__ cbase) {
    __shared__ u32 lcnt[RGSZ];
    int p = blockIdx.x >> 2, rg = blockIdx.x & 3;
    int t = threadIdx.x;
    for (int i = t; i < RGSZ; i += 256) lcnt[i] = 0;
    __syncthreads();
    int base = rg * RGSZ;
    for (int i = t; i < EPP; i += 256) {
        int e = p*EPP + i;
        int r = ei[e];
        u32 rr = (u32)(r - base);
        if (rr < RGSZ) {
            u32 old = atomicAdd(&lcnt[rr], 1u);   // LDS atomic, returns order
            rank[e] = (u16)old;
        }
    }
    __syncthreads();
    u32* dst = cbase + (size_t)p*NNODES + base;
    for (int i = t; i < RGSZ; i += 256) dst[i] = lcnt[i];
}

// per-row: convert 64 partition counts -> exclusive prefix (in place) + total
__global__ __launch_bounds__(256) void k_rowsum(u32* __restrict__ cbase,
                                                u32* __restrict__ cnt) {
    int r = blockIdx.x*256 + threadIdx.x;
    if (r >= NNODES) return;
    u32 running = 0;
    #pragma unroll
    for (int p = 0; p < NPART; ++p) {
        u32 c = cbase[(size_t)p*NNODES + r];
        cbase[(size_t)p*NNODES + r] = running;
        running += c;
    }
    cnt[r] = running;
}

// RANK path: quant (XBLK blocks) + weight GEMMs (192 blocks).
// Fallback: + HB device-atomic histogram blocks in front.
template<bool RANK>
__global__ __launch_bounds__(256) void k_prep(const int* __restrict__ ei,
                                              const float* __restrict__ x,
                                              const float* __restrict__ Wchi,
                                              const float* __restrict__ Wphi,
                                              const float* __restrict__ Wvphi,
                                              u32* __restrict__ cnt,
                                              u16* __restrict__ xb,
                                              char* __restrict__ xq,
                                              float* __restrict__ vsx,
                                              float* __restrict__ wcomb,
                                              u16* __restrict__ gf) {
    int b = blockIdx.x, t = threadIdx.x;
    if (!RANK) {
        if (b < HB) {                              // fallback: device-atomic histogram
            atomicAdd(&cnt[ei[b*256 + t]], 1u);
            return;
        }
        b -= HB;
    }
    if (b < XBLK) {
        // x -> bf16 xb + i8 xq (per-node absmax scale). 1 node per wave.
        int w = t >> 6, lane = t & 63;
        int node = b*4 + w;
        float2 xv = ((const float2*)(x + (size_t)node*DD))[lane];
        u32 pk = (u32)f2b(xv.x) | ((u32)f2b(xv.y) << 16);
        ((u32*)xb)[node*64 + lane] = pk;
        float m = fmaxf(fabsf(xv.x), fabsf(xv.y));
        #pragma unroll
        for (int mask = 1; mask < 64; mask <<= 1)
            m = fmaxf(m, __shfl_xor(m, mask));
        float inv = (m > 0.f) ? 127.f/m : 0.f;
        int q0 = (int)rintf(xv.x*inv), q1 = (int)rintf(xv.y*inv);
        ((u16*)xq)[node*64 + lane] = (u16)((q0 & 0xff) | ((q1 & 0xff) << 8));
        if (lane == 0) vsx[2*node + 1] = m * (1.f/127.f);
        return;
    }
    // weight role: bb<64 -> Wcomb = Wphi@Wchi (fp32 temp);
    //              bb<128 -> Bgram -> frag mat 1;  else Cgram -> frag mat 2
    int bb = b - XBLK;
    if (bb < 64) {
        int idx = bb*256 + t;
        int i = idx >> 7, k = idx & 127;
        float acc = 0.f;
        #pragma unroll 8
        for (int m = 0; m < DD; ++m)
            acc = fmaf(Wphi[i*DD+m], Wchi[m*DD+k], acc);
        wcomb[i*DD+k] = acc;
    } else {
        const float* W = (bb < 128) ? Wvphi : Wchi;
        int mat = (bb < 128) ? 1 : 2;
        int idx = ((bb & 63))*256 + t;
        int a = idx >> 7, c = idx & 127;
        float acc = 0.f;
        #pragma unroll 8
        for (int m = 0; m < DD; ++m)
            acc = fmaf(W[m*DD+a], W[m*DD+c], acc);
        gstore(gf, mat, a, c, acc);
    }
}

// grid NB_SCAN + 64: degree block-sums; extra blocks do Agram -> frag mat 0
__global__ __launch_bounds__(256) void k_scan_bsum(const u32* __restrict__ cnt,
                                                   u32* __restrict__ bsum,
                                                   const float* __restrict__ wcomb,
                                                   u16* __restrict__ gf) {
    if (blockIdx.x >= NB_SCAN) {
        int idx = (blockIdx.x - NB_SCAN)*256 + threadIdx.x;
        int a = idx >> 7, c = idx & 127;
        float acc = 0.f;
        #pragma unroll 8
        for (int m = 0; m < DD; ++m)
            acc = fmaf(wcomb[m*DD+a], wcomb[m*DD+c], acc);
        gstore(gf, 0, a, c, acc);
        return;
    }
    __shared__ u32 s[256];
    int i = blockIdx.x*256 + threadIdx.x;
    s[threadIdx.x] = (i < NNODES) ? cnt[i] : 0u;
    __syncthreads();
    for (int off = 128; off > 0; off >>= 1) {
        if (threadIdx.x < off) s[threadIdx.x] += s[threadIdx.x + off];
        __syncthreads();
    }
    if (threadIdx.x == 0) bsum[blockIdx.x] = s[0];
}

__global__ __launch_bounds__(256) void k_scan_boff(const u32* __restrict__ bsum,
                                                   u32* __restrict__ boff) {
    __shared__ u32 s[256];
    int t = threadIdx.x;
    u32 v = (t < NB_SCAN) ? bsum[t] : 0u;
    s[t] = v;
    __syncthreads();
    for (int off = 1; off < 256; off <<= 1) {
        u32 a = (t >= off) ? s[t - off] : 0u;
        __syncthreads();
        s[t] += a;
        __syncthreads();
    }
    if (t < NB_SCAN) boff[t] = s[t] - v;           // exclusive
}

__global__ __launch_bounds__(256) void k_scan_final(const u32* __restrict__ cnt,
                                                    const u32* __restrict__ boff,
                                                    u32* __restrict__ start,
                                                    u32* __restrict__ cursor) {
    __shared__ u32 s[256];
    int t = threadIdx.x;
    int i = blockIdx.x*256 + t;
    u32 v = (i < NNODES) ? cnt[i] : 0u;
    s[t] = v;
    __syncthreads();
    for (int off = 1; off < 256; off <<= 1) {
        u32 a = (t >= off) ? s[t - off] : 0u;
        __syncthreads();
        s[t] += a;
        __syncthreads();
    }
    if (i < NNODES) {
        u32 val = boff[blockIdx.x] + (s[t] - v);
        start[i]  = val;
        cursor[i] = val;
        if (i == NNODES-1) start[NNODES] = val + v;
    }
}

#define SB (NEDGES/256)       // 6250 scatter blocks
#define GB 782                // gemm blocks: 64 nodes each
// grid = SB + GB = 7032; b%9==0 -> gemm (782 exactly), else scatter

template<bool RANK>
__global__ __launch_bounds__(256) void k_mid(const int* __restrict__ ei,
                                             const float* __restrict__ ew,
                                             const u32* __restrict__ start,
                                             u32* __restrict__ cursor,
                                             const u16* __restrict__ rank,
                                             const u32* __restrict__ cbase,
                                             u32* __restrict__ erec,
                                             const u16* __restrict__ xb,
                                             float* __restrict__ ws,
                                             char* __restrict__ aq,
                                             char* __restrict__ bq,
                                             float* __restrict__ absc) {
    int b = blockIdx.x, t = threadIdx.x;
    if (b % 9 != 0) {                              // scatter into CSR (4B packed record)
        int eb = b - b/9 - 1;
        int e = eb*256 + t;
        int r = __builtin_nontemporal_load(&ei[e]);
        u32 pos;
        if (RANK) {
            int p = e / EPP;                       // partition, same map as k_hist
            pos = start[r] + cbase[(size_t)p*NNODES + r]
                + (u32)__builtin_nontemporal_load(&rank[e]);
        } else {
            pos = atomicAdd(&cursor[r], 1u);
        }
        u32 c  = (u32)__builtin_nontemporal_load(&ei[NEDGES + e]);
        u32 wb = (u32)f2b(__builtin_nontemporal_load(&ew[e])) & 0x7fffu;
        erec[pos] = (c << 15) | wb;                // plain store: let L2 merge lines
        return;
    }
    // gemm role: 4 waves, 16 nodes each, MFMA over the 3 Gram matrices
    __shared__ u16 xs[4][16][DD];
    int w = t >> 6, l = t & 63;
    int l15 = l & 15, lq = l >> 4;
    int nb = (b/9)*64 + w*16;
    if (nb >= NNODES) return;

    const v8s* xbv = (const v8s*)(xb + (size_t)(nb + l15)*DD);
    v8s af[4];
    #pragma unroll
    for (int kk = 0; kk < 4; ++kk) {
        af[kk] = xbv[kk*4 + lq];
        *(v8s*)&xs[w][l15][kk*32 + lq*8] = af[kk];
    }
    const v8s* gf = (const v8s*)ws;                // OFF_GFRAG = 0
    float* phichi = ws + OFF_PHICHI/4;
    float* vsx    = ws + OFF_VSX/4;
    float sa4[4] = {0.f, 0.f, 0.f, 0.f};

    #pragma unroll
    for (int mat = 0; mat < 3; ++mat) {
        v4f acc[8];
        #pragma unroll
        for (int nt = 0; nt < 8; ++nt) acc[nt] = (v4f){0.f,0.f,0.f,0.f};
        #pragma unroll
        for (int kk = 0; kk < 4; ++kk)
            #pragma unroll
            for (int nt = 0; nt < 8; ++nt)
                acc[nt] = __builtin_amdgcn_mfma_f32_16x16x32_bf16(
                    af[kk], gf[((mat*8 + nt)*4 + kk)*64 + l], acc[nt], 0, 0, 0);
        // D[m][n]: m = lq*4 + r (node), n = nt*16 + l15 (dim)
        if (mat < 2) {                             // quantize a/b to i8, per-node scale
            float mx[4] = {0.f, 0.f, 0.f, 0.f};
            #pragma unroll
            for (int nt = 0; nt < 8; ++nt)
                #pragma unroll
                for (int r = 0; r < 4; ++r)
                    mx[r] = fmaxf(mx[r], fabsf(acc[nt][r]));
            #pragma unroll
            for (int mask = 1; mask < 16; mask <<= 1)
                #pragma unroll
                for (int r = 0; r < 4; ++r)
                    mx[r] = fmaxf(mx[r], __shfl_xor(mx[r], mask));
            float iv[4], sc[4];
            #pragma unroll
            for (int r = 0; r < 4; ++r) {
                iv[r] = (mx[r] > 0.f) ? 127.f/mx[r] : 0.f;
                sc[r] = mx[r] * (1.f/127.f);
            }
            char* qdst = mat ? bq : aq;
            #pragma unroll
            for (int nt = 0; nt < 8; ++nt)
                #pragma unroll
                for (int r = 0; r < 4; ++r)
                    qdst[(size_t)(nb + lq*4 + r)*128 + nt*16 + l15] =
                        (char)(int)rintf(acc[nt][r]*iv[r]);
            if (mat == 0) {
                #pragma unroll
                for (int r = 0; r < 4; ++r) sa4[r] = sc[r];
            } else if (l15 == 0) {
                #pragma unroll
                for (int r = 0; r < 4; ++r)
                    *(v2f*)&absc[2*(nb + lq*4 + r)] = (v2f){sa4[r], sc[r]};
            }
        }
        if (mat >= 1) {                            // x . (G x): vsq (mat1), phichi (mat2)
            float p0 = 0.f, p1 = 0.f, p2 = 0.f, p3 = 0.f;
            #pragma unroll
            for (int nt = 0; nt < 8; ++nt) {
                int nn = nt*16 + l15;
                p0 = fmaf(b2f16(xs[w][lq*4+0][nn]), acc[nt][0], p0);
                p1 = fmaf(b2f16(xs[w][lq*4+1][nn]), acc[nt][1], p1);
                p2 = fmaf(b2f16(xs[w][lq*4+2][nn]), acc[nt][2], p2);
                p3 = fmaf(b2f16(xs[w][lq*4+3][nn]), acc[nt][3], p3);
            }
            #pragma unroll
            for (int mask = 1; mask < 16; mask <<= 1) {
                p0 += __shfl_xor(p0, mask);
                p1 += __shfl_xor(p1, mask);
                p2 += __shfl_xor(p2, mask);
                p3 += __shfl_xor(p3, mask);
            }
            if (l15 == 0) {
                int n0 = nb + lq*4;
                if (mat == 1) {
                    vsx[2*(n0+0)] = p0; vsx[2*(n0+1)] = p1;
                    vsx[2*(n0+2)] = p2; vsx[2*(n0+3)] = p3;
                } else {
                    phichi[n0+0] = tanh_pos(sqrtf(fmaxf(p0, 0.f)));
                    phichi[n0+1] = tanh_pos(sqrtf(fmaxf(p1, 0.f)));
                    phichi[n0+2] = tanh_pos(sqrtf(fmaxf(p2, 0.f)));
                    phichi[n0+3] = tanh_pos(sqrtf(fmaxf(p3, 0.f)));
                }
            }
        }
    }
}

// one wave per node; 16 edges per i8-MFMA tile (K=128 via 2 chained MFMAs).
// A rows: 0 = a_r, 1 = b_r (i8), rows 2-15 zero. B cols: 16 gathered i8 x_c.
__global__ __launch_bounds__(256) void k_accum(const float* __restrict__ x,
                                               const float* __restrict__ phichi,
                                               const float* __restrict__ vsx,
                                               const float* __restrict__ absc,
                                               const u32* __restrict__ start,
                                               const u32* __restrict__ erec,
                                               const char* __restrict__ xq,
                                               const char* __restrict__ aq,
                                               const char* __restrict__ bq,
                                               float* __restrict__ out) {
    __shared__ float red[4][8][132];
    int w = threadIdx.x >> 6, lane = threadIdx.x & 63;
    int node = blockIdx.x*4 + w;
    int l15 = lane & 15, lq = lane >> 4;

    u32 s0 = start[node];
    u32 n  = start[node+1] - s0;
    float vq_r = vsx[2*node];
    float2 sab = *(const float2*)&absc[2*node];

    v4i zero4 = {0, 0, 0, 0};
    v4i afr[2];
    {
        const char* src = (l15 == 1) ? bq : aq;
        const v4i* p = (const v4i*)(src + (size_t)node*128);
        bool keep = (l15 < 2);
        #pragma unroll
        for (int kk = 0; kk < 2; ++kk) {
            v4i v = p[kk*4 + lq];
            afr[kk] = keep ? v : zero4;
        }
    }

    float accl[2][16];
    #pragma unroll
    for (int kk = 0; kk < 2; ++kk)
        #pragma unroll
        for (int j = 0; j < 16; ++j) accl[kk][j] = 0.f;
    float sphi = 0.f, wsum = 0.f;

    u32 ntiles = (n + 15) >> 4;

    auto ldr = [&](u32 tt) -> u32 {
        u32 off = tt*16 + (u32)l15;
        u32 eidx = (off < n) ? (s0 + off) : s0;
        return __builtin_nontemporal_load(&erec[eidx]);
    };

    if (ntiles) {
        u32 rc = ldr(0);
        for (u32 tt = 0; tt < ntiles; ++tt) {
            u32 rn = (tt + 1 < ntiles) ? ldr(tt + 1) : rc;
            u32 c = rc >> 15;
            bool valid = (tt*16 + (u32)l15) < n;
            float w_e = valid ? __uint_as_float((rc & 0x7fffu) << 16) : 0.f;
            float2 vx = *(const float2*)&vsx[2*c];   // (vsq_c, sx_c)
            const v4i* xcv = (const v4i*)(xq + (size_t)c*128);
            v4i bfr[2];
            bfr[0] = xcv[lq];
            bfr[1] = xcv[4 + lq];

            v4i d = zero4;
            d = __builtin_amdgcn_mfma_i32_16x16x64_i8(afr[0], bfr[0], d, 0, 0, 0);
            d = __builtin_amdgcn_mfma_i32_16x16x64_i8(afr[1], bfr[1], d, 0, 0, 0);
            // lq==0 lanes: d[0]=adot_int(edge l15), d[1]=bdot_int; others exact 0
            float adot = (float)d[0] * (sab.x * vx.y);
            float bdot = (float)d[1] * (sab.y * vx.y);
            float ss = fmaxf(vq_r + vx.x - 2.f*bdot, 0.f);
            float psi = w_e * tanh_pos(fabsf(adot)) * tanh_pos(__fdividef(1.f, sqrtf(ss) + EPSF));
            float psi_b = __shfl(psi, l15);          // edge l15's psi to all lq groups
            sphi += psi_b;
            wsum += w_e;
            float psx = psi_b * vx.y;                // fold sx_c into the accumulate
            #pragma unroll
            for (int kk = 0; kk < 2; ++kk) {
                const int* pw = (const int*)&bfr[kk];
                #pragma unroll
                for (int wd = 0; wd < 4; ++wd) {
                    int word = pw[wd];
                    accl[kk][wd*4+0] = fmaf(psx, (float)((word << 24) >> 24), accl[kk][wd*4+0]);
                    accl[kk][wd*4+1] = fmaf(psx, (float)((word << 16) >> 24), accl[kk][wd*4+1]);
                    accl[kk][wd*4+2] = fmaf(psx, (float)((word <<  8) >> 24), accl[kk][wd*4+2]);
                    accl[kk][wd*4+3] = fmaf(psx, (float)( word        >> 24), accl[kk][wd*4+3]);
                }
            }
            rc = rn;
        }
    }

    // reduce sphi/wsum over the 16 edge-slots
    #pragma unroll
    for (int mask = 1; mask < 16; mask <<= 1) {
        sphi += __shfl_xor(sphi, mask);
        wsum += __shfl_xor(wsum, mask);
    }

    // pre-reduce accl over adjacent edge-slot pairs, then LDS transpose-reduce
    #pragma unroll
    for (int kk = 0; kk < 2; ++kk)
        #pragma unroll
        for (int j = 0; j < 16; ++j)
            accl[kk][j] += __shfl_xor(accl[kk][j], 1);

    if ((l15 & 1) == 0) {
        int e8 = l15 >> 1;
        #pragma unroll
        for (int kk = 0; kk < 2; ++kk) {
            int base = kk*64 + lq*16;                // dim = kk*64 + lq*16 + j
            *(float4*)&red[w][e8][base]      = *(float4*)&accl[kk][0];
            *(float4*)&red[w][e8][base + 4]  = *(float4*)&accl[kk][4];
            *(float4*)&red[w][e8][base + 8]  = *(float4*)&accl[kk][8];
            *(float4*)&red[w][e8][base + 12] = *(float4*)&accl[kk][12];
        }
    }
    __syncthreads();
    float a0 = 0.f, a1 = 0.f;
    #pragma unroll
    for (int e = 0; e < 8; ++e) {
        float2 v = *(const float2*)&red[w][e][lane*2];
        a0 += v.x; a1 += v.y;
    }

    float ia = (n == 0) ? 0.f : __fdividef(1.f, wsum * phichi[node]);
    float scale = 1.f - ia * sphi;
    float2 xv = *(const float2*)(x + (size_t)node*DD + lane*2);
    v2f o;
    o.x = xv.x*scale + ia*a0;
    o.y = xv.y*scale + ia*a1;
    __builtin_nontemporal_store(o, (v2f*)(out + (size_t)node*DD + lane*2));
}

extern "C" void kernel_launch(void* const* d_in, const int* in_sizes, int n_in,
                              void* d_out, int out_size, void* d_ws, size_t ws_size,
                              hipStream_t stream) {
    const float* x     = (const float*)d_in[0];
    const int*   ei    = (const int*)d_in[1];
    const float* ew    = (const float*)d_in[2];
    const float* Wchi  = (const float*)d_in[3];
    const float* Wphi  = (const float*)d_in[4];
    const float* Wvphi = (const float*)d_in[5];
    float* out = (float*)d_out;
    float* ws  = (float*)d_ws;
    char*  wsb = (char*)d_ws;

    float* phichi = (float*)(wsb + OFF_PHICHI);
    float* vsx    = (float*)(wsb + OFF_VSX);
    u32*   cnt    = (u32*)  (wsb + OFF_CNT);
    u32*   cursor = (u32*)  (wsb + OFF_CNT);    // alias: cnt dead after scans
    u32*   start  = (u32*)  (wsb + OFF_START);
    u32*   bsum   = (u32*)  (wsb + OFF_BSUM);
    u32*   boff   = (u32*)  (wsb + OFF_BOFF);
    u16*   gf     = (u16*)  (wsb + OFF_GFRAG);
    float* absc   = (float*)(wsb + OFF_ABSC);
    char*  aq     = (char*) (wsb + OFF_AQ);
    char*  bq     = (char*) (wsb + OFF_BQ);
    u16*   xb     = (u16*)  (wsb + OFF_XB);
    char*  xq     = (char*) (wsb + OFF_XQ);
    u32*   erec   = (u32*)  (wsb + OFF_EREC);
    float* wcomb  = (float*)(wsb + OFF_WCOMB);  // temp, overlays erec
    u16*   rank   = (u16*)  (wsb + OFF_RANK);
    u32*   cbase  = (u32*)  (wsb + OFF_CBASE);

    bool use_rank = (ws_size >= (size_t)WS_NEED_RANK);

    if (use_rank) {
        k_hist<<<dim3(256), dim3(256), 0, stream>>>(ei, rank, cbase);
        k_prep<true><<<dim3(XBLK+192), dim3(256), 0, stream>>>(ei, x, Wchi, Wphi, Wvphi,
                                                               cnt, xb, xq, vsx, wcomb, gf);
        k_rowsum<<<dim3(NB_SCAN), dim3(256), 0, stream>>>(cbase, cnt);
    } else {
        hipError_t err = hipMemsetAsync(wsb + OFF_CNT, 0, 200000, stream);
        (void)err;
        k_prep<false><<<dim3(HB+XBLK+192), dim3(256), 0, stream>>>(ei, x, Wchi, Wphi, Wvphi,
                                                                   cnt, xb, xq, vsx, wcomb, gf);
    }
    k_scan_bsum<<<dim3(NB_SCAN+64), dim3(256), 0, stream>>>(cnt, bsum, wcomb, gf);
    k_scan_boff<<<dim3(1), dim3(256), 0, stream>>>(bsum, boff);
    k_scan_final<<<dim3(NB_SCAN), dim3(256), 0, stream>>>(cnt, boff, start, cursor);
    if (use_rank) {
        k_mid<true><<<dim3(SB+GB), dim3(256), 0, stream>>>(ei, ew, start, cursor, rank, cbase,
                                                           erec, xb, ws, aq, bq, absc);
    } else {
        k_mid<false><<<dim3(SB+GB), dim3(256), 0, stream>>>(ei, ew, start, cursor, rank, cbase,
                                                            erec, xb, ws, aq, bq, absc);
    }
    k_accum<<<dim3(NNODES/4), dim3(256), 0, stream>>>(x, phichi, vsx, absc, start, erec,
                                                      xq, aq, bq, out);
}

// Round 9
// 219.582 us; speedup vs baseline: 2.1420x; 1.0308x over previous
//
#include <hip/hip_runtime.h>
#include <hip/hip_bf16.h>

#define NNODES 50000
#define NEDGES 1600000
#define DD 128
#define EPSF 1e-6f
#define NB_SCAN 196   // ceil(50000/256)
#define NPART 64      // edge partitions for LDS histogram
#define EPP 25000     // edges per partition (NPART*EPP = NEDGES)
#define RGSZ 12500    // rows per rowgroup (4 rowgroups)

using u32 = unsigned int;
using u16 = unsigned short;
using u64 = unsigned long long;
typedef __attribute__((ext_vector_type(8))) short v8s;   // 8 x bf16 (4 VGPR)
typedef __attribute__((ext_vector_type(4))) float v4f;   // mfma accumulator
typedef __attribute__((ext_vector_type(4))) int   v4i;   // i8 mfma operand (16 i8)
typedef __attribute__((ext_vector_type(2))) float v2f;   // nontemporal-storable pair

static __device__ __forceinline__ float b2f16(u16 v) { return __uint_as_float(((u32)v) << 16); }
static __device__ __forceinline__ u16 f2b(float f) {
    u32 u = __float_as_uint(f);
    return (u16)((u + 0x7fffu + ((u >> 16) & 1u)) >> 16);
}
static __device__ __forceinline__ float tanh_pos(float a) {   // a >= 0, fast
    float e = __expf(-2.f * a);
    return __fdividef(1.f - e, 1.f + e);
}

// workspace byte offsets — ALL gather pools 128B-aligned (R9: xq was 16 mod 128,
// making every 128B record straddle 3 cache lines instead of 2)
#define OFF_GFRAG  0          // 3 * 32KB bf16 Gram matrices in MFMA B-frag layout
#define OFF_PHICHI 98304      // 50000 f32
#define OFF_VSX    298304     // 50000 float2 : (vsq, xscale) per node
#define OFF_CNT    698304     // 50000 u32 row totals (cursor alias in fallback)
#define OFF_START  898304     // 50001 u32 (pad to 200064)
#define OFF_BSUM   1098368    // 196 u32 (pad 1024)
#define OFF_BOFF   1099392    // 196 u32 (pad 1024)
#define OFF_ABSC   1100416    // 50000 float2 : (ascale, bscale)
#define OFF_AQ     1500416    // 50000*128 i8 (128-aligned)
#define OFF_BQ     7900416    // 50000*128 i8 (128-aligned)
#define OFF_XB     14300416   // 50000*128 bf16 (128-aligned)
#define OFF_XQ     27100416   // 50000*128 i8 gather pool (128-aligned!)
#define OFF_EREC   33500416   // 1.6M u32 : (col<<15)|bf16w (64-aligned)
#define OFF_WCOMB  33500416   // 128*128 f32 TEMP, overlays EREC (dead before k_mid)
#define OFF_RANK   39900416   // 1.6M u16 : rank within (partition,row)
#define OFF_CBASE  43100416   // 64*50000 u32 : per-(part,row) counts -> excl bases
#define WS_NEED_RANK 55900416ull

// store val=G[a][c] into MFMA B-fragment layout for mfma_f32_16x16x32_bf16
static __device__ __forceinline__ void gstore(u16* gf, int mat, int a, int c, float v) {
    int lane = (((a >> 3) & 3) << 4) | (c & 15);
    int u = ((((mat*8 + (c >> 4))*4 + (a >> 5))*64 + lane) << 3) | (a & 7);
    gf[u] = f2b(v);
}

#define HB (NEDGES/256)       // 6250 fallback hist blocks
#define XBLK (NNODES/4)       // 12500 x-quant blocks (1 node/wave)

// LDS histogram: 64 partitions x 4 rowgroups = 256 WGs. Zero device-scope atomics.
__global__ __launch_bounds__(256) void k_hist(const int* __restrict__ ei,
                                              u16* __restrict__ rank,
                                              u32* __restrict__ cbase) {
    __shared__ u32 lcnt[RGSZ];
    int p = blockIdx.x >> 2, rg = blockIdx.x & 3;
    int t = threadIdx.x;
    for (int i = t; i < RGSZ; i += 256) lcnt[i] = 0;
    __syncthreads();
    int base = rg * RGSZ;
    for (int i = t; i < EPP; i += 256) {
        int e = p*EPP + i;
        int r = ei[e];
        u32 rr = (u32)(r - base);
        if (rr < RGSZ) {
            u32 old = atomicAdd(&lcnt[rr], 1u);   // LDS atomic, returns order
            rank[e] = (u16)old;
        }
    }
    __syncthreads();
    u32* dst = cbase + (size_t)p*NNODES + base;
    for (int i = t; i < RGSZ; i += 256) dst[i] = lcnt[i];
}

// per-row: convert 64 partition counts -> exclusive prefix (in place) + total
__global__ __launch_bounds__(256) void k_rowsum(u32* __restrict__ cbase,
                                                u32* __restrict__ cnt) {
    int r = blockIdx.x*256 + threadIdx.x;
    if (r >= NNODES) return;
    u32 running = 0;
    #pragma unroll
    for (int p = 0; p < NPART; ++p) {
        u32 c = cbase[(size_t)p*NNODES + r];
        cbase[(size_t)p*NNODES + r] = running;
        running += c;
    }
    cnt[r] = running;
}

// RANK path: quant (XBLK blocks) + weight GEMMs (192 blocks).
// Fallback: + HB device-atomic histogram blocks in front.
template<bool RANK>
__global__ __launch_bounds__(256) void k_prep(const int* __restrict__ ei,
                                              const float* __restrict__ x,
                                              const float* __restrict__ Wchi,
                                              const float* __restrict__ Wphi,
                                              const float* __restrict__ Wvphi,
                                              u32* __restrict__ cnt,
                                              u16* __restrict__ xb,
                                              char* __restrict__ xq,
                                              float* __restrict__ vsx,
                                              float* __restrict__ wcomb,
                                              u16* __restrict__ gf) {
    int b = blockIdx.x, t = threadIdx.x;
    if (!RANK) {
        if (b < HB) {                              // fallback: device-atomic histogram
            atomicAdd(&cnt[ei[b*256 + t]], 1u);
            return;
        }
        b -= HB;
    }
    if (b < XBLK) {
        // x -> bf16 xb + i8 xq (per-node absmax scale). 1 node per wave.
        int w = t >> 6, lane = t & 63;
        int node = b*4 + w;
        float2 xv = ((const float2*)(x + (size_t)node*DD))[lane];
        u32 pk = (u32)f2b(xv.x) | ((u32)f2b(xv.y) << 16);
        ((u32*)xb)[node*64 + lane] = pk;
        float m = fmaxf(fabsf(xv.x), fabsf(xv.y));
        #pragma unroll
        for (int mask = 1; mask < 64; mask <<= 1)
            m = fmaxf(m, __shfl_xor(m, mask));
        float inv = (m > 0.f) ? 127.f/m : 0.f;
        int q0 = (int)rintf(xv.x*inv), q1 = (int)rintf(xv.y*inv);
        ((u16*)xq)[node*64 + lane] = (u16)((q0 & 0xff) | ((q1 & 0xff) << 8));
        if (lane == 0) vsx[2*node + 1] = m * (1.f/127.f);
        return;
    }
    // weight role: bb<64 -> Wcomb = Wphi@Wchi (fp32 temp);
    //              bb<128 -> Bgram -> frag mat 1;  else Cgram -> frag mat 2
    int bb = b - XBLK;
    if (bb < 64) {
        int idx = bb*256 + t;
        int i = idx >> 7, k = idx & 127;
        float acc = 0.f;
        #pragma unroll 8
        for (int m = 0; m < DD; ++m)
            acc = fmaf(Wphi[i*DD+m], Wchi[m*DD+k], acc);
        wcomb[i*DD+k] = acc;
    } else {
        const float* W = (bb < 128) ? Wvphi : Wchi;
        int mat = (bb < 128) ? 1 : 2;
        int idx = ((bb & 63))*256 + t;
        int a = idx >> 7, c = idx & 127;
        float acc = 0.f;
        #pragma unroll 8
        for (int m = 0; m < DD; ++m)
            acc = fmaf(W[m*DD+a], W[m*DD+c], acc);
        gstore(gf, mat, a, c, acc);
    }
}

// grid NB_SCAN + 64: degree block-sums; extra blocks do Agram -> frag mat 0
__global__ __launch_bounds__(256) void k_scan_bsum(const u32* __restrict__ cnt,
                                                   u32* __restrict__ bsum,
                                                   const float* __restrict__ wcomb,
                                                   u16* __restrict__ gf) {
    if (blockIdx.x >= NB_SCAN) {
        int idx = (blockIdx.x - NB_SCAN)*256 + threadIdx.x;
        int a = idx >> 7, c = idx & 127;
        float acc = 0.f;
        #pragma unroll 8
        for (int m = 0; m < DD; ++m)
            acc = fmaf(wcomb[m*DD+a], wcomb[m*DD+c], acc);
        gstore(gf, 0, a, c, acc);
        return;
    }
    __shared__ u32 s[256];
    int i = blockIdx.x*256 + threadIdx.x;
    s[threadIdx.x] = (i < NNODES) ? cnt[i] : 0u;
    __syncthreads();
    for (int off = 128; off > 0; off >>= 1) {
        if (threadIdx.x < off) s[threadIdx.x] += s[threadIdx.x + off];
        __syncthreads();
    }
    if (threadIdx.x == 0) bsum[blockIdx.x] = s[0];
}

__global__ __launch_bounds__(256) void k_scan_boff(const u32* __restrict__ bsum,
                                                   u32* __restrict__ boff) {
    __shared__ u32 s[256];
    int t = threadIdx.x;
    u32 v = (t < NB_SCAN) ? bsum[t] : 0u;
    s[t] = v;
    __syncthreads();
    for (int off = 1; off < 256; off <<= 1) {
        u32 a = (t >= off) ? s[t - off] : 0u;
        __syncthreads();
        s[t] += a;
        __syncthreads();
    }
    if (t < NB_SCAN) boff[t] = s[t] - v;           // exclusive
}

__global__ __launch_bounds__(256) void k_scan_final(const u32* __restrict__ cnt,
                                                    const u32* __restrict__ boff,
                                                    u32* __restrict__ start,
                                                    u32* __restrict__ cursor) {
    __shared__ u32 s[256];
    int t = threadIdx.x;
    int i = blockIdx.x*256 + t;
    u32 v = (i < NNODES) ? cnt[i] : 0u;
    s[t] = v;
    __syncthreads();
    for (int off = 1; off < 256; off <<= 1) {
        u32 a = (t >= off) ? s[t - off] : 0u;
        __syncthreads();
        s[t] += a;
        __syncthreads();
    }
    if (i < NNODES) {
        u32 val = boff[blockIdx.x] + (s[t] - v);
        start[i]  = val;
        cursor[i] = val;
        if (i == NNODES-1) start[NNODES] = val + v;
    }
}

#define SB (NEDGES/256)       // 6250 scatter blocks
#define GB 782                // gemm blocks: 64 nodes each
// grid = SB + GB = 7032; b%9==0 -> gemm (782 exactly), else scatter

template<bool RANK>
__global__ __launch_bounds__(256) void k_mid(const int* __restrict__ ei,
                                             const float* __restrict__ ew,
                                             const u32* __restrict__ start,
                                             u32* __restrict__ cursor,
                                             const u16* __restrict__ rank,
                                             const u32* __restrict__ cbase,
                                             u32* __restrict__ erec,
                                             const u16* __restrict__ xb,
                                             float* __restrict__ ws,
                                             char* __restrict__ aq,
                                             char* __restrict__ bq,
                                             float* __restrict__ absc) {
    int b = blockIdx.x, t = threadIdx.x;
    if (b % 9 != 0) {                              // scatter into CSR (4B packed record)
        int eb = b - b/9 - 1;
        int e = eb*256 + t;
        int r = __builtin_nontemporal_load(&ei[e]);
        u32 pos;
        if (RANK) {
            int p = e / EPP;                       // partition, same map as k_hist
            pos = start[r] + cbase[(size_t)p*NNODES + r]
                + (u32)__builtin_nontemporal_load(&rank[e]);
        } else {
            pos = atomicAdd(&cursor[r], 1u);
        }
        u32 c  = (u32)__builtin_nontemporal_load(&ei[NEDGES + e]);
        u32 wb = (u32)f2b(__builtin_nontemporal_load(&ew[e])) & 0x7fffu;
        erec[pos] = (c << 15) | wb;                // plain store: let L2 merge lines
        return;
    }
    // gemm role: 4 waves, 16 nodes each, MFMA over the 3 Gram matrices
    __shared__ u16 xs[4][16][DD];
    int w = t >> 6, l = t & 63;
    int l15 = l & 15, lq = l >> 4;
    int nb = (b/9)*64 + w*16;
    if (nb >= NNODES) return;

    const v8s* xbv = (const v8s*)(xb + (size_t)(nb + l15)*DD);
    v8s af[4];
    #pragma unroll
    for (int kk = 0; kk < 4; ++kk) {
        af[kk] = xbv[kk*4 + lq];
        *(v8s*)&xs[w][l15][kk*32 + lq*8] = af[kk];
    }
    const v8s* gf = (const v8s*)ws;                // OFF_GFRAG = 0
    float* phichi = ws + OFF_PHICHI/4;
    float* vsx    = ws + OFF_VSX/4;
    float sa4[4] = {0.f, 0.f, 0.f, 0.f};

    #pragma unroll
    for (int mat = 0; mat < 3; ++mat) {
        v4f acc[8];
        #pragma unroll
        for (int nt = 0; nt < 8; ++nt) acc[nt] = (v4f){0.f,0.f,0.f,0.f};
        #pragma unroll
        for (int kk = 0; kk < 4; ++kk)
            #pragma unroll
            for (int nt = 0; nt < 8; ++nt)
                acc[nt] = __builtin_amdgcn_mfma_f32_16x16x32_bf16(
                    af[kk], gf[((mat*8 + nt)*4 + kk)*64 + l], acc[nt], 0, 0, 0);
        // D[m][n]: m = lq*4 + r (node), n = nt*16 + l15 (dim)
        if (mat < 2) {                             // quantize a/b to i8, per-node scale
            float mx[4] = {0.f, 0.f, 0.f, 0.f};
            #pragma unroll
            for (int nt = 0; nt < 8; ++nt)
                #pragma unroll
                for (int r = 0; r < 4; ++r)
                    mx[r] = fmaxf(mx[r], fabsf(acc[nt][r]));
            #pragma unroll
            for (int mask = 1; mask < 16; mask <<= 1)
                #pragma unroll
                for (int r = 0; r < 4; ++r)
                    mx[r] = fmaxf(mx[r], __shfl_xor(mx[r], mask));
            float iv[4], sc[4];
            #pragma unroll
            for (int r = 0; r < 4; ++r) {
                iv[r] = (mx[r] > 0.f) ? 127.f/mx[r] : 0.f;
                sc[r] = mx[r] * (1.f/127.f);
            }
            char* qdst = mat ? bq : aq;
            #pragma unroll
            for (int nt = 0; nt < 8; ++nt)
                #pragma unroll
                for (int r = 0; r < 4; ++r)
                    qdst[(size_t)(nb + lq*4 + r)*128 + nt*16 + l15] =
                        (char)(int)rintf(acc[nt][r]*iv[r]);
            if (mat == 0) {
                #pragma unroll
                for (int r = 0; r < 4; ++r) sa4[r] = sc[r];
            } else if (l15 == 0) {
                #pragma unroll
                for (int r = 0; r < 4; ++r)
                    *(v2f*)&absc[2*(nb + lq*4 + r)] = (v2f){sa4[r], sc[r]};
            }
        }
        if (mat >= 1) {                            // x . (G x): vsq (mat1), phichi (mat2)
            float p0 = 0.f, p1 = 0.f, p2 = 0.f, p3 = 0.f;
            #pragma unroll
            for (int nt = 0; nt < 8; ++nt) {
                int nn = nt*16 + l15;
                p0 = fmaf(b2f16(xs[w][lq*4+0][nn]), acc[nt][0], p0);
                p1 = fmaf(b2f16(xs[w][lq*4+1][nn]), acc[nt][1], p1);
                p2 = fmaf(b2f16(xs[w][lq*4+2][nn]), acc[nt][2], p2);
                p3 = fmaf(b2f16(xs[w][lq*4+3][nn]), acc[nt][3], p3);
            }
            #pragma unroll
            for (int mask = 1; mask < 16; mask <<= 1) {
                p0 += __shfl_xor(p0, mask);
                p1 += __shfl_xor(p1, mask);
                p2 += __shfl_xor(p2, mask);
                p3 += __shfl_xor(p3, mask);
            }
            if (l15 == 0) {
                int n0 = nb + lq*4;
                if (mat == 1) {
                    vsx[2*(n0+0)] = p0; vsx[2*(n0+1)] = p1;
                    vsx[2*(n0+2)] = p2; vsx[2*(n0+3)] = p3;
                } else {
                    phichi[n0+0] = tanh_pos(sqrtf(fmaxf(p0, 0.f)));
                    phichi[n0+1] = tanh_pos(sqrtf(fmaxf(p1, 0.f)));
                    phichi[n0+2] = tanh_pos(sqrtf(fmaxf(p2, 0.f)));
                    phichi[n0+3] = tanh_pos(sqrtf(fmaxf(p3, 0.f)));
                }
            }
        }
    }
}

// one wave per node; 16 edges per i8-MFMA tile (K=128 via 2 chained MFMAs).
// R9: software-pipelined — erec 2-deep, xq/vsx data 1-deep prefetch.
__global__ __launch_bounds__(256) void k_accum(const float* __restrict__ x,
                                               const float* __restrict__ phichi,
                                               const float* __restrict__ vsx,
                                               const float* __restrict__ absc,
                                               const u32* __restrict__ start,
                                               const u32* __restrict__ erec,
                                               const char* __restrict__ xq,
                                               const char* __restrict__ aq,
                                               const char* __restrict__ bq,
                                               float* __restrict__ out) {
    __shared__ float red[4][8][132];
    int w = threadIdx.x >> 6, lane = threadIdx.x & 63;
    int node = blockIdx.x*4 + w;
    int l15 = lane & 15, lq = lane >> 4;

    u32 s0 = start[node];
    u32 n  = start[node+1] - s0;
    float vq_r = vsx[2*node];
    float2 sab = *(const float2*)&absc[2*node];

    v4i zero4 = {0, 0, 0, 0};
    v4i afr[2];
    {
        const char* src = (l15 == 1) ? bq : aq;
        const v4i* p = (const v4i*)(src + (size_t)node*128);
        bool keep = (l15 < 2);
        #pragma unroll
        for (int kk = 0; kk < 2; ++kk) {
            v4i v = p[kk*4 + lq];
            afr[kk] = keep ? v : zero4;
        }
    }

    float accl[2][16];
    #pragma unroll
    for (int kk = 0; kk < 2; ++kk)
        #pragma unroll
        for (int j = 0; j < 16; ++j) accl[kk][j] = 0.f;
    float sphi = 0.f, wsum = 0.f;

    u32 ntiles = (n + 15) >> 4;

    auto ldr = [&](u32 tt) -> u32 {
        u32 off = tt*16 + (u32)l15;
        u32 eidx = (off < n) ? (s0 + off) : s0;
        return __builtin_nontemporal_load(&erec[eidx]);
    };

    if (ntiles) {
        u32 rc = ldr(0);
        u32 rn = (ntiles > 1) ? ldr(1) : rc;
        // preload tile 0's gather data
        v4i pb0, pb1; float2 pvx;
        {
            u32 c0 = rc >> 15;
            const v4i* xcv = (const v4i*)(xq + (size_t)c0*128);
            pb0 = xcv[lq]; pb1 = xcv[4 + lq];
            pvx = *(const float2*)&vsx[2*c0];
        }
        for (u32 tt = 0; tt < ntiles; ++tt) {
            v4i b0 = pb0, b1 = pb1;
            float2 vx = pvx;
            u32 cur = rc;
            u32 rnn = (tt + 2 < ntiles) ? ldr(tt + 2) : rn;
            if (tt + 1 < ntiles) {                 // issue next tile's gather NOW
                u32 c1 = rn >> 15;
                const v4i* xcv = (const v4i*)(xq + (size_t)c1*128);
                pb0 = xcv[lq]; pb1 = xcv[4 + lq];
                pvx = *(const float2*)&vsx[2*c1];
            }
            rc = rn; rn = rnn;

            bool valid = (tt*16 + (u32)l15) < n;
            float w_e = valid ? __uint_as_float((cur & 0x7fffu) << 16) : 0.f;

            v4i d = zero4;
            d = __builtin_amdgcn_mfma_i32_16x16x64_i8(afr[0], b0, d, 0, 0, 0);
            d = __builtin_amdgcn_mfma_i32_16x16x64_i8(afr[1], b1, d, 0, 0, 0);
            // lq==0 lanes: d[0]=adot_int(edge l15), d[1]=bdot_int; others exact 0
            float adot = (float)d[0] * (sab.x * vx.y);
            float bdot = (float)d[1] * (sab.y * vx.y);
            float ss = fmaxf(vq_r + vx.x - 2.f*bdot, 0.f);
            float psi = w_e * tanh_pos(fabsf(adot)) * tanh_pos(__fdividef(1.f, sqrtf(ss) + EPSF));
            float psi_b = __shfl(psi, l15);        // edge l15's psi to all lq groups
            sphi += psi_b;
            wsum += w_e;
            float psx = psi_b * vx.y;              // fold sx_c into the accumulate
            #pragma unroll
            for (int kk = 0; kk < 2; ++kk) {
                const int* pw = (const int*)((kk == 0) ? &b0 : &b1);
                #pragma unroll
                for (int wd = 0; wd < 4; ++wd) {
                    int word = pw[wd];
                    accl[kk][wd*4+0] = fmaf(psx, (float)((word << 24) >> 24), accl[kk][wd*4+0]);
                    accl[kk][wd*4+1] = fmaf(psx, (float)((word << 16) >> 24), accl[kk][wd*4+1]);
                    accl[kk][wd*4+2] = fmaf(psx, (float)((word <<  8) >> 24), accl[kk][wd*4+2]);
                    accl[kk][wd*4+3] = fmaf(psx, (float)( word        >> 24), accl[kk][wd*4+3]);
                }
            }
        }
    }

    // reduce sphi/wsum over the 16 edge-slots
    #pragma unroll
    for (int mask = 1; mask < 16; mask <<= 1) {
        sphi += __shfl_xor(sphi, mask);
        wsum += __shfl_xor(wsum, mask);
    }

    // pre-reduce accl over adjacent edge-slot pairs, then LDS transpose-reduce
    #pragma unroll
    for (int kk = 0; kk < 2; ++kk)
        #pragma unroll
        for (int j = 0; j < 16; ++j)
            accl[kk][j] += __shfl_xor(accl[kk][j], 1);

    if ((l15 & 1) == 0) {
        int e8 = l15 >> 1;
        #pragma unroll
        for (int kk = 0; kk < 2; ++kk) {
            int base = kk*64 + lq*16;              // dim = kk*64 + lq*16 + j
            *(float4*)&red[w][e8][base]      = *(float4*)&accl[kk][0];
            *(float4*)&red[w][e8][base + 4]  = *(float4*)&accl[kk][4];
            *(float4*)&red[w][e8][base + 8]  = *(float4*)&accl[kk][8];
            *(float4*)&red[w][e8][base + 12] = *(float4*)&accl[kk][12];
        }
    }
    __syncthreads();
    float a0 = 0.f, a1 = 0.f;
    #pragma unroll
    for (int e = 0; e < 8; ++e) {
        float2 v = *(const float2*)&red[w][e][lane*2];
        a0 += v.x; a1 += v.y;
    }

    float ia = (n == 0) ? 0.f : __fdividef(1.f, wsum * phichi[node]);
    float scale = 1.f - ia * sphi;
    float2 xv = *(const float2*)(x + (size_t)node*DD + lane*2);
    v2f o;
    o.x = xv.x*scale + ia*a0;
    o.y = xv.y*scale + ia*a1;
    __builtin_nontemporal_store(o, (v2f*)(out + (size_t)node*DD + lane*2));
}

extern "C" void kernel_launch(void* const* d_in, const int* in_sizes, int n_in,
                              void* d_out, int out_size, void* d_ws, size_t ws_size,
                              hipStream_t stream) {
    const float* x     = (const float*)d_in[0];
    const int*   ei    = (const int*)d_in[1];
    const float* ew    = (const float*)d_in[2];
    const float* Wchi  = (const float*)d_in[3];
    const float* Wphi  = (const float*)d_in[4];
    const float* Wvphi = (const float*)d_in[5];
    float* out = (float*)d_out;
    float* ws  = (float*)d_ws;
    char*  wsb = (char*)d_ws;

    float* phichi = (float*)(wsb + OFF_PHICHI);
    float* vsx    = (float*)(wsb + OFF_VSX);
    u32*   cnt    = (u32*)  (wsb + OFF_CNT);
    u32*   cursor = (u32*)  (wsb + OFF_CNT);    // alias: cnt dead after scans
    u32*   start  = (u32*)  (wsb + OFF_START);
    u32*   bsum   = (u32*)  (wsb + OFF_BSUM);
    u32*   boff   = (u32*)  (wsb + OFF_BOFF);
    u16*   gf     = (u16*)  (wsb + OFF_GFRAG);
    float* absc   = (float*)(wsb + OFF_ABSC);
    char*  aq     = (char*) (wsb + OFF_AQ);
    char*  bq     = (char*) (wsb + OFF_BQ);
    u16*   xb     = (u16*)  (wsb + OFF_XB);
    char*  xq     = (char*) (wsb + OFF_XQ);
    u32*   erec   = (u32*)  (wsb + OFF_EREC);
    float* wcomb  = (float*)(wsb + OFF_WCOMB);  // temp, overlays erec
    u16*   rank   = (u16*)  (wsb + OFF_RANK);
    u32*   cbase  = (u32*)  (wsb + OFF_CBASE);

    bool use_rank = (ws_size >= (size_t)WS_NEED_RANK);

    if (use_rank) {
        k_hist<<<dim3(256), dim3(256), 0, stream>>>(ei, rank, cbase);
        k_prep<true><<<dim3(XBLK+192), dim3(256), 0, stream>>>(ei, x, Wchi, Wphi, Wvphi,
                                                               cnt, xb, xq, vsx, wcomb, gf);
        k_rowsum<<<dim3(NB_SCAN), dim3(256), 0, stream>>>(cbase, cnt);
    } else {
        hipError_t err = hipMemsetAsync(wsb + OFF_CNT, 0, 200000, stream);
        (void)err;
        k_prep<false><<<dim3(HB+XBLK+192), dim3(256), 0, stream>>>(ei, x, Wchi, Wphi, Wvphi,
                                                                   cnt, xb, xq, vsx, wcomb, gf);
    }
    k_scan_bsum<<<dim3(NB_SCAN+64), dim3(256), 0, stream>>>(cnt, bsum, wcomb, gf);
    k_scan_boff<<<dim3(1), dim3(256), 0, stream>>>(bsum, boff);
    k_scan_final<<<dim3(NB_SCAN), dim3(256), 0, stream>>>(cnt, boff, start, cursor);
    if (use_rank) {
        k_mid<true><<<dim3(SB+GB), dim3(256), 0, stream>>>(ei, ew, start, cursor, rank, cbase,
                                                           erec, xb, ws, aq, bq, absc);
    } else {
        k_mid<false><<<dim3(SB+GB), dim3(256), 0, stream>>>(ei, ew, start, cursor, rank, cbase,
                                                            erec, xb, ws, aq, bq, absc);
    }
    k_accum<<<dim3(NNODES/4), dim3(256), 0, stream>>>(x, phichi, vsx, absc, start, erec,
                                                      xq, aq, bq, out);
}